// Round 2
// baseline (18307.539 us; speedup 1.0000x reference)
//
#include <hip/hip_runtime.h>
#include <math.h>

#define B_ 32
#define S_ 128
#define H_ 512
#define V_ 32000
#define G4_ 2048
#define KS_ 16          // k segments for gates partials
#define NBLK 500        // logits blocks, 64 cols each
#define VPB 64

typedef __attribute__((ext_vector_type(8))) short bf8;   // 8 x bf16 fragment
typedef __attribute__((ext_vector_type(4))) float f4;    // MFMA accumulator

__device__ __forceinline__ unsigned short f2bf(float x) {
    union { float f; unsigned u; } v; v.f = x;
    unsigned r = v.u + 0x7FFFu + ((v.u >> 16) & 1u);     // RNE
    return (unsigned short)(r >> 16);
}
__device__ __forceinline__ float bf2f(unsigned short b) {
    union { unsigned u; float f; } v; v.u = ((unsigned)b) << 16; return v.f;
}
__device__ __forceinline__ float4 ldf4(const float* p) {
    return *reinterpret_cast<const float4*>(p);
}

// ---------------- init: copy h0, c0 ----------------
__global__ __launch_bounds__(256) void k_init(float* __restrict__ h, float* __restrict__ c,
                                              const float* __restrict__ h0,
                                              const float* __restrict__ c0) {
    int i = blockIdx.x * 256 + threadIdx.x;
    h[i] = h0[i];
    c[i] = c0[i];
}

// ---------------- split W_out into bf16 hi/lo (once) ----------------
__global__ __launch_bounds__(256) void k_wsplit(const float* __restrict__ W,
                                                unsigned short* __restrict__ Wh,
                                                unsigned short* __restrict__ Wl) {
    size_t i = ((size_t)blockIdx.x * 256 + threadIdx.x) * 4;
    float4 w = ldf4(W + i);
    ushort4 hi, lo;
    hi.x = f2bf(w.x); lo.x = f2bf(w.x - bf2f(hi.x));
    hi.y = f2bf(w.y); lo.y = f2bf(w.y - bf2f(hi.y));
    hi.z = f2bf(w.z); lo.z = f2bf(w.z - bf2f(hi.z));
    hi.w = f2bf(w.w); lo.w = f2bf(w.w - bf2f(hi.w));
    *reinterpret_cast<ushort4*>(Wh + i) = hi;
    *reinterpret_cast<ushort4*>(Wl + i) = lo;
}

// ---------------- gates partials (fp32, includes emb @ W_ih part) ----------------
// gp[ks][b][j] = sum_{k in seg ks} ( h[b][k]*W_hh[j][k] + emb[tok_b_s][k]*W_ih[j][k] )
__device__ void gates_body(int gblk, int w, int lane,
                           const float* __restrict__ Whh, const float* __restrict__ Wih,
                           const float* __restrict__ emb, const int* __restrict__ inputs,
                           int s, const float* __restrict__ h, float* __restrict__ gp) {
    const int j = ((gblk & 7) * 4 + w) * 64 + lane;
    const int ks = gblk >> 3, k0 = ks * 32;
    int tok[B_];
#pragma unroll
    for (int b = 0; b < B_; ++b) tok[b] = inputs[b * S_ + s];
    float acc[B_];
#pragma unroll
    for (int b = 0; b < B_; ++b) acc[b] = 0.f;
#pragma unroll
    for (int kk = 0; kk < 32; kk += 4) {
        float4 a = ldf4(Whh + (size_t)j * H_ + k0 + kk);
        float4 cw = ldf4(Wih + (size_t)j * H_ + k0 + kk);
#pragma unroll
        for (int b = 0; b < B_; ++b) {
            float4 hv = ldf4(h + b * H_ + k0 + kk);
            float4 xv = ldf4(emb + (size_t)tok[b] * H_ + k0 + kk);
            acc[b] += a.x * hv.x + a.y * hv.y + a.z * hv.z + a.w * hv.w
                    + cw.x * xv.x + cw.y * xv.y + cw.z * xv.z + cw.w * xv.w;
        }
    }
#pragma unroll
    for (int b = 0; b < B_; ++b)
        gp[((size_t)ks * B_ + b) * G4_ + j] = acc[b];
}

// ---------------- big per-step kernel: [gates t+1] + [MFMA logits + softmax partials] ----
// blocks 0..127: gates partials for step t+1 (fp32, reads fp32 h)
// blocks 128..627: logits block of 64 cols, 3-term bf16 MFMA, fused online softmax/argmax
__global__ __launch_bounds__(256) void k_big(const int* __restrict__ inputs,
                                             const float* __restrict__ h,
                                             const unsigned short* __restrict__ hh,
                                             const unsigned short* __restrict__ hl,
                                             const unsigned short* __restrict__ Wh,
                                             const unsigned short* __restrict__ Wl,
                                             const float* __restrict__ Whh,
                                             const float* __restrict__ Wih,
                                             const float* __restrict__ emb,
                                             const float* __restrict__ b_out,
                                             float* __restrict__ gp,
                                             float* __restrict__ sp,
                                             int t, int do_gates) {
    const int tid = threadIdx.x;
    if (blockIdx.x < 128) {
        if (do_gates)
            gates_body(blockIdx.x, tid >> 6, tid & 63, Whh, Wih, emb, inputs, t + 1, h, gp);
        return;
    }
    const int pblk = blockIdx.x - 128;
    const int v0 = pblk * VPB;
    const int w = tid >> 6, lane = tid & 63;
    const int c = lane & 15, kg = lane >> 4;

    // --- MFMA phase: wave w owns n-tile of 16 cols [v0+w*16, +16), all K, 2 m-tiles ---
    f4 acc0 = {0.f, 0.f, 0.f, 0.f}, acc1 = {0.f, 0.f, 0.f, 0.f};
    const unsigned short* wph = Wh + (size_t)(v0 + w * 16 + c) * H_;
    const unsigned short* wpl = Wl + (size_t)(v0 + w * 16 + c) * H_;
    const unsigned short* a0h = hh + (size_t)c * H_;
    const unsigned short* a1h = hh + (size_t)(c + 16) * H_;
    const unsigned short* a0l = hl + (size_t)c * H_;
    const unsigned short* a1l = hl + (size_t)(c + 16) * H_;
#pragma unroll 2
    for (int kc = 0; kc < 16; ++kc) {
        const int ko = kc * 32 + kg * 8;
        bf8 Bh = *reinterpret_cast<const bf8*>(wph + ko);
        bf8 Bl = *reinterpret_cast<const bf8*>(wpl + ko);
        bf8 A0h = *reinterpret_cast<const bf8*>(a0h + ko);
        bf8 A1h = *reinterpret_cast<const bf8*>(a1h + ko);
        bf8 A0l = *reinterpret_cast<const bf8*>(a0l + ko);
        bf8 A1l = *reinterpret_cast<const bf8*>(a1l + ko);
        acc0 = __builtin_amdgcn_mfma_f32_16x16x32_bf16(A0h, Bh, acc0, 0, 0, 0);
        acc1 = __builtin_amdgcn_mfma_f32_16x16x32_bf16(A1h, Bh, acc1, 0, 0, 0);
        acc0 = __builtin_amdgcn_mfma_f32_16x16x32_bf16(A0l, Bh, acc0, 0, 0, 0);
        acc1 = __builtin_amdgcn_mfma_f32_16x16x32_bf16(A1l, Bh, acc1, 0, 0, 0);
        acc0 = __builtin_amdgcn_mfma_f32_16x16x32_bf16(A0h, Bl, acc0, 0, 0, 0);
        acc1 = __builtin_amdgcn_mfma_f32_16x16x32_bf16(A1h, Bl, acc1, 0, 0, 0);
    }

    // --- deposit C tiles to LDS: D mapping col=lane&15, row=(lane>>4)*4+reg ---
    __shared__ float slds[B_][VPB + 4];
#pragma unroll
    for (int r = 0; r < 4; ++r) {
        slds[kg * 4 + r][w * 16 + c] = acc0[r];
        slds[16 + kg * 4 + r][w * 16 + c] = acc1[r];
    }
    __syncthreads();

    // --- fused online softmax / argmax / target over this block's 64 cols ---
    const int b = tid >> 3, sub = tid & 7;
    const int tok = inputs[b * S_ + t];
    float m = -INFINITY, s = 0.f, mv = -INFINITY, tv = -INFINITY;
    int mi = 0x7fffffff;
#pragma unroll
    for (int q = 0; q < 8; ++q) {
        const int vl = sub * 8 + q, v = v0 + vl;
        float x = slds[b][vl] + b_out[v];
        float nm = fmaxf(m, x);
        s = s * __expf(m - nm) + __expf(x - nm);
        m = nm;
        if (x > mv) { mv = x; mi = v; }   // ascending v, strict > -> first max
        if (v == tok) tv = x;
    }
#pragma unroll
    for (int off = 1; off < 8; off <<= 1) {
        float cm = __shfl_xor(m, off), cs = __shfl_xor(s, off);
        float cmv = __shfl_xor(mv, off), ctv = __shfl_xor(tv, off);
        int cmi = __shfl_xor(mi, off);
        float nm = fmaxf(m, cm);
        s = s * __expf(m - nm) + cs * __expf(cm - nm);
        m = nm;
        if (cmv > mv || (cmv == mv && cmi < mi)) { mv = cmv; mi = cmi; }
        tv = fmaxf(tv, ctv);
    }
    if (sub == 0) {
        float* o = sp + ((size_t)b * NBLK + pblk) * 5;
        o[0] = m; o[1] = s; o[2] = mv; o[3] = (float)mi; o[4] = tv;
    }
}

// ---------------- cell update (blocks 0..63) + finish previous step (blocks 64..95) ------
__global__ __launch_bounds__(256) void k_cell(const float* __restrict__ gp,
                                              const float* __restrict__ b_ih,
                                              const float* __restrict__ b_hh,
                                              float* __restrict__ h, float* __restrict__ c,
                                              unsigned short* __restrict__ hh,
                                              unsigned short* __restrict__ hl,
                                              const float* __restrict__ sp,
                                              float* __restrict__ out,
                                              float* __restrict__ lossbuf,
                                              int t, int do_cell, int do_finish) {
    const int tid = threadIdx.x;
    if (blockIdx.x < 64) {
        if (!do_cell) return;
        const int b = blockIdx.x >> 1;
        const int n = ((blockIdx.x & 1) << 8) + tid;
        float g4[4];
#pragma unroll
        for (int gi = 0; gi < 4; ++gi) {
            const int j = gi * H_ + n;
            float s = b_ih[j] + b_hh[j];
#pragma unroll
            for (int ks = 0; ks < KS_; ++ks) s += gp[((size_t)ks * B_ + b) * G4_ + j];
            g4[gi] = s;
        }
        const float ig = 1.f / (1.f + expf(-g4[0]));
        const float fg = 1.f / (1.f + expf(-g4[1]));
        const float gg = tanhf(g4[2]);
        const float og = 1.f / (1.f + expf(-g4[3]));
        const float cn = fg * c[b * H_ + n] + ig * gg;
        c[b * H_ + n] = cn;
        const float hn = og * tanhf(cn);
        h[b * H_ + n] = hn;
        const unsigned short hb = f2bf(hn);
        hh[b * H_ + n] = hb;
        hl[b * H_ + n] = f2bf(hn - bf2f(hb));
    } else {
        if (!do_finish) return;
        const int b = blockIdx.x - 64;     // 0..31
        const int tp = t - 1;              // the step being finished
        float m = -INFINITY, s = 0.f, mv = -INFINITY, tv = -INFINITY;
        int mi = 0x7fffffff;
        for (int i = tid; i < NBLK; i += 256) {
            const float* o = sp + ((size_t)b * NBLK + i) * 5;
            float cm = o[0], cs = o[1], cmv = o[2], ctv = o[4];
            int cmi = (int)o[3];
            float nm = fmaxf(m, cm);
            s = s * expf(m - nm) + cs * expf(cm - nm);
            m = nm;
            if (cmv > mv || (cmv == mv && cmi < mi)) { mv = cmv; mi = cmi; }
            tv = fmaxf(tv, ctv);
        }
        __shared__ float sm[256], ss[256], smv[256], stv[256];
        __shared__ int smi[256];
        sm[tid] = m; ss[tid] = s; smv[tid] = mv; smi[tid] = mi; stv[tid] = tv;
        __syncthreads();
        for (int off = 128; off > 0; off >>= 1) {
            if (tid < off) {
                float cm = sm[tid + off], cs = ss[tid + off];
                float cmv = smv[tid + off], ctv = stv[tid + off];
                int cmi = smi[tid + off];
                float nm = fmaxf(sm[tid], cm);
                ss[tid] = ss[tid] * expf(sm[tid] - nm) + cs * expf(cm - nm);
                sm[tid] = nm;
                if (cmv > smv[tid] || (cmv == smv[tid] && cmi < smi[tid])) {
                    smv[tid] = cmv; smi[tid] = cmi;
                }
                stv[tid] = fmaxf(stv[tid], ctv);
            }
            __syncthreads();
        }
        if (tid == 0) {
            const float logZ = sm[0] + logf(ss[0]);
            out[1 + b * S_ + tp] = (float)smi[0];
            lossbuf[tp * B_ + b] = stv[0] - logZ;
        }
    }
}

// ---------------- final: deterministic sum of per-row losses ----------------
__global__ __launch_bounds__(256) void k_sum(const float* __restrict__ lossbuf,
                                             float* __restrict__ out) {
    const int tid = threadIdx.x;
    float a = 0.f;
    for (int i = tid; i < B_ * S_; i += 256) a += lossbuf[i];
    __shared__ float red[256];
    red[tid] = a;
    __syncthreads();
    for (int off = 128; off > 0; off >>= 1) {
        if (tid < off) red[tid] += red[tid + off];
        __syncthreads();
    }
    if (tid == 0) out[0] = -red[0] / (float)B_;
}

extern "C" void kernel_launch(void* const* d_in, const int* in_sizes, int n_in,
                              void* d_out, int out_size, void* d_ws, size_t ws_size,
                              hipStream_t stream) {
    const int*   inputs = (const int*)d_in[0];
    const float* h0     = (const float*)d_in[3];
    const float* c0     = (const float*)d_in[4];
    const float* emb    = (const float*)d_in[5];
    const float* W_ih   = (const float*)d_in[6];
    const float* W_hh   = (const float*)d_in[7];
    const float* b_ih   = (const float*)d_in[8];
    const float* b_hh   = (const float*)d_in[9];
    const float* W_out  = (const float*)d_in[10];
    const float* b_out  = (const float*)d_in[11];
    float* out = (float*)d_out;

    char* p = (char*)d_ws;
    auto alloc = [&](size_t bytes) { char* r = p; p += (bytes + 255) & ~255ull; return r; };
    float* h        = (float*)alloc((size_t)B_ * H_ * 4);
    float* cst      = (float*)alloc((size_t)B_ * H_ * 4);
    float* lossbuf  = (float*)alloc((size_t)B_ * S_ * 4);
    float* gp       = (float*)alloc((size_t)KS_ * B_ * G4_ * 4);
    float* sp       = (float*)alloc((size_t)B_ * NBLK * 5 * 4);
    unsigned short* hh = (unsigned short*)alloc((size_t)B_ * H_ * 2);
    unsigned short* hl = (unsigned short*)alloc((size_t)B_ * H_ * 2);
    unsigned short* Wh = (unsigned short*)alloc((size_t)V_ * H_ * 2);
    unsigned short* Wl = (unsigned short*)alloc((size_t)V_ * H_ * 2);

    k_init<<<64, 256, 0, stream>>>(h, cst, h0, c0);
    k_wsplit<<<(V_ * H_) / (256 * 4), 256, 0, stream>>>(W_out, Wh, Wl);
    // initial gates from h0, tokens of step 0 (gates-only: grid covers blocks 0..127)
    k_big<<<128, 256, 0, stream>>>(inputs, h, hh, hl, Wh, Wl, W_hh, W_ih, emb,
                                   b_out, gp, sp, -1, 1);
    for (int t = 0; t < S_; ++t) {
        k_cell<<<96, 256, 0, stream>>>(gp, b_ih, b_hh, h, cst, hh, hl, sp, out,
                                       lossbuf, t, 1, (t > 0) ? 1 : 0);
        k_big<<<128 + NBLK, 256, 0, stream>>>(inputs, h, hh, hl, Wh, Wl, W_hh, W_ih,
                                              emb, b_out, gp, sp, t, (t < S_ - 1) ? 1 : 0);
    }
    k_cell<<<96, 256, 0, stream>>>(gp, b_ih, b_hh, h, cst, hh, hl, sp, out,
                                   lossbuf, S_, 0, 1);
    k_sum<<<1, 256, 0, stream>>>(lossbuf, out);
}

// Round 4
// 15870.378 us; speedup vs baseline: 1.1536x; 1.1536x over previous
//
#include <hip/hip_runtime.h>
#include <math.h>

#define B_ 32
#define S_ 128
#define H_ 512
#define V_ 32000
#define G4_ 2048
#define KS_ 16          // k segments for gates partials
#define NTILE 500       // logits tiles of 64 cols
#define NBLK_P 256      // persistent blocks (1 per CU)
#define NGRP 8          // barrier tree groups
#define NTASK (NTILE + 128)

typedef __attribute__((ext_vector_type(8))) short bf8;   // 8 x bf16 fragment
typedef __attribute__((ext_vector_type(4))) float f4;    // MFMA accumulator

__device__ __forceinline__ unsigned short f2bf(float x) {
    union { float f; unsigned u; } v; v.f = x;
    unsigned r = v.u + 0x7FFFu + ((v.u >> 16) & 1u);     // RNE
    return (unsigned short)(r >> 16);
}
__device__ __forceinline__ float bf2f(unsigned short b) {
    union { unsigned u; float f; } v; v.u = ((unsigned)b) << 16; return v.f;
}
__device__ __forceinline__ float4 ldf4(const float* p) {
    return *reinterpret_cast<const float4*>(p);
}

// ---------------- two-level device-scope grid barrier ----------------
// bar layout (ints): group counters at bar[g*16] (g<8), root at bar[128], gen at bar[160]
__device__ __forceinline__ void gridbar(int* bar, int blk) {
    __syncthreads();
    if (threadIdx.x == 0) {
        __threadfence();
        int* gen = bar + 160;
        int g = __hip_atomic_load(gen, __ATOMIC_RELAXED, __HIP_MEMORY_SCOPE_AGENT);
        bool released = false;
        if (__hip_atomic_fetch_add(bar + (blk >> 5) * 16, 1, __ATOMIC_ACQ_REL,
                                   __HIP_MEMORY_SCOPE_AGENT) == 31) {
            if (__hip_atomic_fetch_add(bar + 128, 1, __ATOMIC_ACQ_REL,
                                       __HIP_MEMORY_SCOPE_AGENT) == NGRP - 1) {
                __hip_atomic_store(bar + 128, 0, __ATOMIC_RELAXED, __HIP_MEMORY_SCOPE_AGENT);
                for (int i = 0; i < NGRP; ++i)
                    __hip_atomic_store(bar + i * 16, 0, __ATOMIC_RELAXED,
                                       __HIP_MEMORY_SCOPE_AGENT);
                __hip_atomic_fetch_add(gen, 1, __ATOMIC_RELEASE, __HIP_MEMORY_SCOPE_AGENT);
                released = true;
            }
        }
        if (!released) {
            int spins = 0;
            while (__hip_atomic_load(gen, __ATOMIC_ACQUIRE, __HIP_MEMORY_SCOPE_AGENT) == g) {
                __builtin_amdgcn_s_sleep(4);
                if (++spins > (1 << 16)) break;   // safety valve: never hang forever
            }
        }
        __threadfence();
    }
    __syncthreads();
}

// ---------------- split W_out into bf16 hi/lo (once) ----------------
__global__ __launch_bounds__(256) void k_wsplit(const float* __restrict__ W,
                                                unsigned short* __restrict__ Wh,
                                                unsigned short* __restrict__ Wl) {
    size_t i = ((size_t)blockIdx.x * 256 + threadIdx.x) * 4;
    float4 w = ldf4(W + i);
    ushort4 hi, lo;
    hi.x = f2bf(w.x); lo.x = f2bf(w.x - bf2f(hi.x));
    hi.y = f2bf(w.y); lo.y = f2bf(w.y - bf2f(hi.y));
    hi.z = f2bf(w.z); lo.z = f2bf(w.z - bf2f(hi.z));
    hi.w = f2bf(w.w); lo.w = f2bf(w.w - bf2f(hi.w));
    *reinterpret_cast<ushort4*>(Wh + i) = hi;
    *reinterpret_cast<ushort4*>(Wl + i) = lo;
}

// ------- precompute XW[t][b][j] = emb[tok[b,t]] @ W_ih^T + b_ih + b_hh (once) -------
// LDS-staged emb rows (16 at a time) -> broadcast reads, no scalar-load storms.
__global__ __launch_bounds__(256) void k_xw(const int* __restrict__ inputs,
                                            const float* __restrict__ emb,
                                            const float* __restrict__ W_ih,
                                            const float* __restrict__ b_ih,
                                            const float* __restrict__ b_hh,
                                            float* __restrict__ XW) {
    __shared__ float es[16 * H_];
    const int tid = threadIdx.x;
    const int j = blockIdx.x * 256 + tid;
    const int t = blockIdx.y;
    const float bias = b_ih[j] + b_hh[j];
#pragma unroll
    for (int half = 0; half < 2; ++half) {
        __syncthreads();
        for (int idx = tid; idx < 16 * 128; idx += 256) {
            int b = idx >> 7, k4 = (idx & 127) << 2;
            int tok = inputs[(half * 16 + b) * S_ + t];
            *reinterpret_cast<float4*>(&es[b * H_ + k4]) = ldf4(emb + (size_t)tok * H_ + k4);
        }
        __syncthreads();
        float acc[16];
#pragma unroll
        for (int b = 0; b < 16; ++b) acc[b] = 0.f;
        for (int k = 0; k < H_; k += 4) {
            float4 wv = ldf4(W_ih + (size_t)j * H_ + k);
#pragma unroll
            for (int b = 0; b < 16; ++b) {
                float4 xv = *reinterpret_cast<const float4*>(&es[b * H_ + k]);
                acc[b] += wv.x * xv.x + wv.y * xv.y + wv.z * xv.z + wv.w * xv.w;
            }
        }
#pragma unroll
        for (int b = 0; b < 16; ++b)
            XW[(size_t)(t * B_ + half * 16 + b) * G4_ + j] = acc[b] + bias;
    }
}

// ---------------- gates task: gp[ks][b][j] = sum_{k in seg ks} h[b][k]*W_hh[j][k] ----
// 128 tasks: (jc 0..7) x (ks 0..15). h segment staged in LDS (broadcast reads).
__device__ void gates_task(int g, int tid, const float* __restrict__ Whh,
                           const float* __restrict__ h, float* __restrict__ gp,
                           float* __restrict__ smem) {
    __syncthreads();
    const int jc = g & 7, ks = g >> 3, k0 = ks * 32;
    {
        const int b = tid >> 3, k4 = (tid & 7) * 4;
        *reinterpret_cast<float4*>(&smem[b * 32 + k4]) = ldf4(h + b * H_ + k0 + k4);
    }
    __syncthreads();
    const int j = jc * 256 + tid;
    float acc[B_];
#pragma unroll
    for (int b = 0; b < B_; ++b) acc[b] = 0.f;
#pragma unroll
    for (int kk = 0; kk < 32; kk += 4) {
        float4 wv = ldf4(Whh + (size_t)j * H_ + k0 + kk);
#pragma unroll
        for (int b = 0; b < B_; ++b) {
            float4 hv = *reinterpret_cast<const float4*>(&smem[b * 32 + kk]);
            acc[b] += wv.x * hv.x + wv.y * hv.y + wv.z * hv.z + wv.w * hv.w;
        }
    }
#pragma unroll
    for (int b = 0; b < B_; ++b)
        gp[((size_t)ks * B_ + b) * G4_ + j] = acc[b];
}

// ---------------- logits tile: 64 cols, 3-term bf16 MFMA + fused softmax partials ----
__device__ void logits_tile(int pblk, int tid, const int* __restrict__ inputs,
                            const unsigned short* __restrict__ hh,
                            const unsigned short* __restrict__ hl,
                            const unsigned short* __restrict__ Wh,
                            const unsigned short* __restrict__ Wl,
                            const float* __restrict__ b_out,
                            float* __restrict__ sp, int t, float* __restrict__ smem) {
    __syncthreads();
    const int v0 = pblk * 64;
    const int w = tid >> 6, lane = tid & 63;
    const int c = lane & 15, kg = lane >> 4;
    f4 acc0 = {0.f, 0.f, 0.f, 0.f}, acc1 = {0.f, 0.f, 0.f, 0.f};
    const unsigned short* wph = Wh + (size_t)(v0 + w * 16 + c) * H_;
    const unsigned short* wpl = Wl + (size_t)(v0 + w * 16 + c) * H_;
    const unsigned short* a0h = hh + (size_t)c * H_;
    const unsigned short* a1h = hh + (size_t)(c + 16) * H_;
    const unsigned short* a0l = hl + (size_t)c * H_;
    const unsigned short* a1l = hl + (size_t)(c + 16) * H_;
#pragma unroll 2
    for (int kc = 0; kc < 16; ++kc) {
        const int ko = kc * 32 + kg * 8;
        bf8 Bh = *reinterpret_cast<const bf8*>(wph + ko);
        bf8 Bl = *reinterpret_cast<const bf8*>(wpl + ko);
        bf8 A0h = *reinterpret_cast<const bf8*>(a0h + ko);
        bf8 A1h = *reinterpret_cast<const bf8*>(a1h + ko);
        bf8 A0l = *reinterpret_cast<const bf8*>(a0l + ko);
        bf8 A1l = *reinterpret_cast<const bf8*>(a1l + ko);
        acc0 = __builtin_amdgcn_mfma_f32_16x16x32_bf16(A0h, Bh, acc0, 0, 0, 0);
        acc1 = __builtin_amdgcn_mfma_f32_16x16x32_bf16(A1h, Bh, acc1, 0, 0, 0);
        acc0 = __builtin_amdgcn_mfma_f32_16x16x32_bf16(A0l, Bh, acc0, 0, 0, 0);
        acc1 = __builtin_amdgcn_mfma_f32_16x16x32_bf16(A1l, Bh, acc1, 0, 0, 0);
        acc0 = __builtin_amdgcn_mfma_f32_16x16x32_bf16(A0h, Bl, acc0, 0, 0, 0);
        acc1 = __builtin_amdgcn_mfma_f32_16x16x32_bf16(A1h, Bl, acc1, 0, 0, 0);
    }
    float (*slds)[68] = (float (*)[68])smem;
#pragma unroll
    for (int r = 0; r < 4; ++r) {
        slds[kg * 4 + r][w * 16 + c] = acc0[r];
        slds[16 + kg * 4 + r][w * 16 + c] = acc1[r];
    }
    __syncthreads();
    const int b = tid >> 3, sub = tid & 7;
    const int tok = inputs[b * S_ + t];
    float m = -INFINITY, s = 0.f, mv = -INFINITY, tv = -INFINITY;
    int mi = 0x7fffffff;
#pragma unroll
    for (int q = 0; q < 8; ++q) {
        const int vl = sub * 8 + q, v = v0 + vl;
        float x = slds[b][vl] + b_out[v];
        float nm = fmaxf(m, x);
        s = s * __expf(m - nm) + __expf(x - nm);
        m = nm;
        if (x > mv) { mv = x; mi = v; }
        if (v == tok) tv = x;
    }
#pragma unroll
    for (int off = 1; off < 8; off <<= 1) {
        float cm = __shfl_xor(m, off), cs = __shfl_xor(s, off);
        float cmv = __shfl_xor(mv, off), ctv = __shfl_xor(tv, off);
        int cmi = __shfl_xor(mi, off);
        float nm = fmaxf(m, cm);
        s = s * __expf(m - nm) + cs * __expf(cm - nm);
        m = nm;
        if (cmv > mv || (cmv == mv && cmi < mi)) { mv = cmv; mi = cmi; }
        tv = fmaxf(tv, ctv);
    }
    if (sub == 0) {
        float* o = sp + ((size_t)b * NTILE + pblk) * 5;
        o[0] = m; o[1] = s; o[2] = mv; o[3] = (float)mi; o[4] = tv;
    }
}

// ---------------- cell: reduce gates partials + XW, activations, update h/c ---------
__device__ void cell_body(int blk, int tid, int t, const float* __restrict__ XW,
                          const float* __restrict__ gp, float* __restrict__ h,
                          float* __restrict__ c, unsigned short* __restrict__ hh,
                          unsigned short* __restrict__ hl) {
    const int b = blk >> 1;
    const int n = ((blk & 1) << 8) + tid;
    float g4[4];
#pragma unroll
    for (int gi = 0; gi < 4; ++gi) {
        const int j = gi * H_ + n;
        float s = XW[(size_t)(t * B_ + b) * G4_ + j];
#pragma unroll
        for (int ks = 0; ks < KS_; ++ks) s += gp[((size_t)ks * B_ + b) * G4_ + j];
        g4[gi] = s;
    }
    const float ig = 1.f / (1.f + expf(-g4[0]));
    const float fg = 1.f / (1.f + expf(-g4[1]));
    const float gg = tanhf(g4[2]);
    const float og = 1.f / (1.f + expf(-g4[3]));
    const float cn = fg * c[b * H_ + n] + ig * gg;
    c[b * H_ + n] = cn;
    const float hn = og * tanhf(cn);
    h[b * H_ + n] = hn;
    const unsigned short hb = f2bf(hn);
    hh[b * H_ + n] = hb;
    hl[b * H_ + n] = f2bf(hn - bf2f(hb));
}

// ---------------- finish: merge tile partials for one batch row of step tp ----------
__device__ void finish_body(int b, int tid, int tp, const float* __restrict__ sp,
                            float* __restrict__ out, float* __restrict__ lossbuf,
                            float* __restrict__ smem) {
    __syncthreads();
    float m = -INFINITY, s = 0.f, mv = -INFINITY, tv = -INFINITY;
    int mi = 0x7fffffff;
    for (int i = tid; i < NTILE; i += 256) {
        const float* o = sp + ((size_t)b * NTILE + i) * 5;
        float cm = o[0], cs = o[1], cmv = o[2], ctv = o[4];
        int cmi = (int)o[3];
        float nm = fmaxf(m, cm);
        s = s * expf(m - nm) + cs * expf(cm - nm);
        m = nm;
        if (cmv > mv || (cmv == mv && cmi < mi)) { mv = cmv; mi = cmi; }
        tv = fmaxf(tv, ctv);
    }
    float* sm = smem;
    float* ss = smem + 256;
    float* smv = smem + 512;
    float* stv = smem + 768;
    int* smi = (int*)(smem + 1024);
    sm[tid] = m; ss[tid] = s; smv[tid] = mv; smi[tid] = mi; stv[tid] = tv;
    __syncthreads();
    for (int off = 128; off > 0; off >>= 1) {
        if (tid < off) {
            float cm = sm[tid + off], cs = ss[tid + off];
            float cmv = smv[tid + off], ctv = stv[tid + off];
            int cmi = smi[tid + off];
            float nm = fmaxf(sm[tid], cm);
            ss[tid] = ss[tid] * expf(sm[tid] - nm) + cs * expf(cm - nm);
            sm[tid] = nm;
            if (cmv > smv[tid] || (cmv == smv[tid] && cmi < smi[tid])) {
                smv[tid] = cmv; smi[tid] = cmi;
            }
            stv[tid] = fmaxf(stv[tid], ctv);
        }
        __syncthreads();
    }
    if (tid == 0) {
        const float logZ = sm[0] + logf(ss[0]);
        out[1 + b * S_ + tp] = (float)smi[0];
        lossbuf[tp * B_ + b] = stv[0] - logZ;
    }
    __syncthreads();
}

// ---------------- the persistent kernel (256 blocks, manual grid barrier) -----------
__global__ __launch_bounds__(256)
void k_persist(const int* __restrict__ inputs, const float* __restrict__ h0,
               const float* __restrict__ c0, const float* __restrict__ Whh,
               const unsigned short* __restrict__ Wh, const unsigned short* __restrict__ Wl,
               const float* __restrict__ b_out, const float* __restrict__ XW,
               float* __restrict__ h, float* __restrict__ c,
               unsigned short* __restrict__ hh, unsigned short* __restrict__ hl,
               float* __restrict__ gp, float* __restrict__ sp,
               float* __restrict__ lossbuf, float* __restrict__ out, int* bar) {
    __shared__ float smem[2176];
    const int blk = blockIdx.x, tid = threadIdx.x;

    // prologue: init h, c from h0, c0 (64 elems per block)
    if (tid < 64) { int i = blk * 64 + tid; h[i] = h0[i]; c[i] = c0[i]; }
    gridbar(bar, blk);
    // initial gates partials from h(-1) = h0
    if (blk < 128) gates_task(blk, tid, Whh, h, gp, smem);
    gridbar(bar, blk);

    for (int t = 0; t < S_; ++t) {
        // phase 1: cell(t) produces h_t; finish(t-1)
        if (blk < 64) cell_body(blk, tid, t, XW, gp, h, c, hh, hl);
        else if (blk < 96) { if (t > 0) finish_body(blk - 64, tid, t - 1, sp, out, lossbuf, smem); }
        gridbar(bar, blk);
        // phase 2: logits(t) on h_t + gates(t+1) on h_t
        for (int task = blk; task < NTASK; task += NBLK_P) {
            if (task < NTILE) logits_tile(task, tid, inputs, hh, hl, Wh, Wl, b_out, sp, t, smem);
            else if (t < S_ - 1) gates_task(task - NTILE, tid, Whh, h, gp, smem);
        }
        gridbar(bar, blk);
    }
    if (blk >= 64 && blk < 96) finish_body(blk - 64, tid, S_ - 1, sp, out, lossbuf, smem);
    gridbar(bar, blk);
    if (blk == 0) {
        float a = 0.f;
        for (int i = tid; i < B_ * S_; i += 256) a += lossbuf[i];
        smem[tid] = a;
        __syncthreads();
        for (int off = 128; off > 0; off >>= 1) {
            if (tid < off) smem[tid] += smem[tid + off];
            __syncthreads();
        }
        if (tid == 0) out[0] = -smem[0] / (float)B_;
    }
}

extern "C" void kernel_launch(void* const* d_in, const int* in_sizes, int n_in,
                              void* d_out, int out_size, void* d_ws, size_t ws_size,
                              hipStream_t stream) {
    const int*   inputs = (const int*)d_in[0];
    const float* h0     = (const float*)d_in[3];
    const float* c0     = (const float*)d_in[4];
    const float* emb    = (const float*)d_in[5];
    const float* W_ih   = (const float*)d_in[6];
    const float* W_hh   = (const float*)d_in[7];
    const float* b_ih   = (const float*)d_in[8];
    const float* b_hh   = (const float*)d_in[9];
    const float* W_out  = (const float*)d_in[10];
    const float* b_out  = (const float*)d_in[11];
    float* out = (float*)d_out;

    char* p = (char*)d_ws;
    auto alloc = [&](size_t bytes) { char* r = p; p += (bytes + 255) & ~255ull; return r; };
    float* h        = (float*)alloc((size_t)B_ * H_ * 4);
    float* cst      = (float*)alloc((size_t)B_ * H_ * 4);
    float* lossbuf  = (float*)alloc((size_t)B_ * S_ * 4);
    float* gp       = (float*)alloc((size_t)KS_ * B_ * G4_ * 4);
    float* sp       = (float*)alloc((size_t)B_ * NTILE * 5 * 4);
    int*   bar      = (int*)alloc(1024);
    unsigned short* hh = (unsigned short*)alloc((size_t)B_ * H_ * 2);
    unsigned short* hl = (unsigned short*)alloc((size_t)B_ * H_ * 2);
    unsigned short* Wh = (unsigned short*)alloc((size_t)V_ * H_ * 2);
    unsigned short* Wl = (unsigned short*)alloc((size_t)V_ * H_ * 2);
    float* XW       = (float*)alloc((size_t)S_ * B_ * G4_ * 4);

    hipMemsetAsync(bar, 0, 1024, stream);
    k_wsplit<<<(V_ * H_) / (256 * 4), 256, 0, stream>>>(W_out, Wh, Wl);
    k_xw<<<dim3(8, S_), 256, 0, stream>>>(inputs, emb, W_ih, b_ih, b_hh, XW);
    k_persist<<<NBLK_P, 256, 0, stream>>>(inputs, h0, c0, W_hh, Wh, Wl, b_out, XW,
                                          h, cst, hh, hl, gp, sp, lossbuf, out, bar);
}

// Round 5
// 6887.405 us; speedup vs baseline: 2.6581x; 2.3043x over previous
//
#include <hip/hip_runtime.h>
#include <math.h>

#define B_ 32
#define S_ 128
#define H_ 512
#define V_ 32000
#define G4_ 2048
#define KS_ 16          // k segments for gates partials
#define NVT 2000        // 16-col v-tiles
#define NGB 500         // gemm blocks (64 cols each)
#define NBLK_R 128      // recurrence persistent blocks
#define NGRP_R 4        // 128 blocks / 32 per group

typedef __attribute__((ext_vector_type(8))) short bf8;   // 8 x bf16 fragment
typedef __attribute__((ext_vector_type(4))) float f4;    // MFMA accumulator

__device__ __forceinline__ unsigned short f2bf(float x) {
    union { float f; unsigned u; } v; v.f = x;
    unsigned r = v.u + 0x7FFFu + ((v.u >> 16) & 1u);     // RNE
    return (unsigned short)(r >> 16);
}
__device__ __forceinline__ float bf2f(unsigned short b) {
    union { unsigned u; float f; } v; v.u = ((unsigned)b) << 16; return v.f;
}
__device__ __forceinline__ float4 ldf4(const float* p) {
    return *reinterpret_cast<const float4*>(p);
}

// ---------------- two-level device-scope grid barrier (validated in R4) -------------
// bar ints: group counters bar[g*16] (g<NGRP_R), root bar[128], gen bar[160]
__device__ __forceinline__ void gridbar(int* bar, int blk) {
    __syncthreads();
    if (threadIdx.x == 0) {
        __threadfence();
        int* gen = bar + 160;
        int g = __hip_atomic_load(gen, __ATOMIC_RELAXED, __HIP_MEMORY_SCOPE_AGENT);
        bool released = false;
        if (__hip_atomic_fetch_add(bar + (blk >> 5) * 16, 1, __ATOMIC_ACQ_REL,
                                   __HIP_MEMORY_SCOPE_AGENT) == 31) {
            if (__hip_atomic_fetch_add(bar + 128, 1, __ATOMIC_ACQ_REL,
                                       __HIP_MEMORY_SCOPE_AGENT) == NGRP_R - 1) {
                __hip_atomic_store(bar + 128, 0, __ATOMIC_RELAXED, __HIP_MEMORY_SCOPE_AGENT);
                for (int i = 0; i < NGRP_R; ++i)
                    __hip_atomic_store(bar + i * 16, 0, __ATOMIC_RELAXED,
                                       __HIP_MEMORY_SCOPE_AGENT);
                __hip_atomic_fetch_add(gen, 1, __ATOMIC_RELEASE, __HIP_MEMORY_SCOPE_AGENT);
                released = true;
            }
        }
        if (!released) {
            int spins = 0;
            while (__hip_atomic_load(gen, __ATOMIC_ACQUIRE, __HIP_MEMORY_SCOPE_AGENT) == g) {
                __builtin_amdgcn_s_sleep(2);
                if (++spins > (1 << 17)) break;   // safety valve
            }
        }
        __threadfence();
    }
    __syncthreads();
}

// ------ split W_out into bf16 hi/lo, PRE-SWIZZLED into MFMA B-fragment order --------
// Wp[((vt*16 + kc)*64 + lane)*8 + e] = W[(vt*16 + (lane&15))*H + kc*32 + (lane>>4)*8 + e]
__global__ __launch_bounds__(256) void k_wsplit(const float* __restrict__ W,
                                                unsigned short* __restrict__ Wph,
                                                unsigned short* __restrict__ Wpl) {
    const size_t id = (size_t)blockIdx.x * 256 + threadIdx.x;   // 0 .. NVT*16*64-1
    const int lane = (int)(id & 63);
    const size_t fc = id >> 6;            // vt*16 + kc
    const int kc = (int)(fc & 15);
    const size_t vt = fc >> 4;
    const size_t r = vt * 16 + (lane & 15);
    const int k0 = kc * 32 + (lane >> 4) * 8;
    const float* src = W + r * H_ + k0;
    bf8 hv, lv;
#pragma unroll
    for (int e = 0; e < 8; ++e) {
        float x = src[e];
        unsigned short hb = f2bf(x);
        hv[e] = (short)hb;
        lv[e] = (short)f2bf(x - bf2f(hb));
    }
    *reinterpret_cast<bf8*>(Wph + id * 8) = hv;
    *reinterpret_cast<bf8*>(Wpl + id * 8) = lv;
}

// ------- precompute XW[t][b][j] = emb[tok[b,t]] @ W_ih^T + b_ih + b_hh (once) -------
__global__ __launch_bounds__(256) void k_xw(const int* __restrict__ inputs,
                                            const float* __restrict__ emb,
                                            const float* __restrict__ W_ih,
                                            const float* __restrict__ b_ih,
                                            const float* __restrict__ b_hh,
                                            float* __restrict__ XW) {
    __shared__ float es[16 * H_];
    const int tid = threadIdx.x;
    const int j = blockIdx.x * 256 + tid;
    const int t = blockIdx.y;
    const float bias = b_ih[j] + b_hh[j];
#pragma unroll
    for (int half = 0; half < 2; ++half) {
        __syncthreads();
        for (int idx = tid; idx < 16 * 128; idx += 256) {
            int b = idx >> 7, k4 = (idx & 127) << 2;
            int tok = inputs[(half * 16 + b) * S_ + t];
            *reinterpret_cast<float4*>(&es[b * H_ + k4]) = ldf4(emb + (size_t)tok * H_ + k4);
        }
        __syncthreads();
        float acc[16];
#pragma unroll
        for (int b = 0; b < 16; ++b) acc[b] = 0.f;
        for (int k = 0; k < H_; k += 4) {
            float4 wv = ldf4(W_ih + (size_t)j * H_ + k);
#pragma unroll
            for (int b = 0; b < 16; ++b) {
                float4 xv = *reinterpret_cast<const float4*>(&es[b * H_ + k]);
                acc[b] += wv.x * xv.x + wv.y * xv.y + wv.z * xv.z + wv.w * xv.w;
            }
        }
#pragma unroll
        for (int b = 0; b < 16; ++b)
            XW[(size_t)(t * B_ + half * 16 + b) * G4_ + j] = acc[b] + bias;
    }
}

// ---------------- gates task: gp[ks][b][j] = sum_{k in seg ks} h[b][k]*W_hh[j][k] ----
// block == task (fixed) -> each block's 32 KB W_hh slice stays L1-resident across steps.
__device__ void gates_task(int g, int tid, const float* __restrict__ Whh,
                           const float* __restrict__ h, float* __restrict__ gp,
                           float* __restrict__ smem) {
    __syncthreads();
    const int jc = g & 7, ks = g >> 3, k0 = ks * 32;
    {
        const int b = tid >> 3, k4 = (tid & 7) * 4;
        *reinterpret_cast<float4*>(&smem[b * 32 + k4]) = ldf4(h + b * H_ + k0 + k4);
    }
    __syncthreads();
    const int j = jc * 256 + tid;
    float acc[B_];
#pragma unroll
    for (int b = 0; b < B_; ++b) acc[b] = 0.f;
#pragma unroll
    for (int kk = 0; kk < 32; kk += 4) {
        float4 wv = ldf4(Whh + (size_t)j * H_ + k0 + kk);
#pragma unroll
        for (int b = 0; b < B_; ++b) {
            float4 hv = *reinterpret_cast<const float4*>(&smem[b * 32 + kk]);
            acc[b] += wv.x * hv.x + wv.y * hv.y + wv.z * hv.z + wv.w * hv.w;
        }
    }
#pragma unroll
    for (int b = 0; b < B_; ++b)
        gp[((size_t)ks * B_ + b) * G4_ + j] = acc[b];
}

// ------ cell: reduce gp + XW, activations, update h/c, emit A-fragments (bf16 hi/lo) -
__device__ void cell_body(int blk, int tid, int t, const float* __restrict__ XW,
                          const float* __restrict__ gp, float* __restrict__ h,
                          float* __restrict__ c, unsigned short* __restrict__ Ah,
                          unsigned short* __restrict__ Al) {
    const int b = blk >> 1;
    const int n = ((blk & 1) << 8) + tid;
    float g4[4];
#pragma unroll
    for (int gi = 0; gi < 4; ++gi) {
        const int j = gi * H_ + n;
        float s = XW[(size_t)(t * B_ + b) * G4_ + j];
#pragma unroll
        for (int ks = 0; ks < KS_; ++ks) s += gp[((size_t)ks * B_ + b) * G4_ + j];
        g4[gi] = s;
    }
    const float ig = 1.f / (1.f + expf(-g4[0]));
    const float fg = 1.f / (1.f + expf(-g4[1]));
    const float gg = tanhf(g4[2]);
    const float og = 1.f / (1.f + expf(-g4[3]));
    const float cn = fg * c[b * H_ + n] + ig * gg;
    c[b * H_ + n] = cn;
    const float hn = og * tanhf(cn);
    h[b * H_ + n] = hn;
    // A-fragment scatter: lane = kg*16 + (b&15), elem e, half = b>>4
    const unsigned short hb = f2bf(hn);
    const unsigned short lb = f2bf(hn - bf2f(hb));
    const int kc = n >> 5, kk = n & 31, kg = kk >> 3, e = kk & 7;
    const int half = b >> 4, lane = kg * 16 + (b & 15);
    const size_t idx = ((((size_t)t * 16 + kc) * 2 + half) * 64 + lane) * 8 + e;
    Ah[idx] = hb;
    Al[idx] = lb;
}

// ---------------- recurrence-only persistent kernel (128 blocks) ----------------
__global__ __launch_bounds__(256)
void k_recur(const float* __restrict__ h0, const float* __restrict__ c0,
             const float* __restrict__ Whh, const float* __restrict__ XW,
             float* __restrict__ h, float* __restrict__ c,
             unsigned short* __restrict__ Ah, unsigned short* __restrict__ Al,
             float* __restrict__ gp, int* bar) {
    __shared__ float smem[B_ * 32];
    const int blk = blockIdx.x, tid = threadIdx.x;
    if (tid < 128) { int i = blk * 128 + tid; h[i] = h0[i]; c[i] = c0[i]; }
    gridbar(bar, blk);
    gates_task(blk, tid, Whh, h, gp, smem);          // gates for t=0 from h0
    for (int t = 0; t < S_; ++t) {
        gridbar(bar, blk);                           // gp ready
        if (blk < 64) cell_body(blk, tid, t, XW, gp, h, c, Ah, Al);
        gridbar(bar, blk);                           // h_t ready
        if (t < S_ - 1) gates_task(blk, tid, Whh, h, gp, smem);
    }
}

// ------- batched logits GEMM (3-term bf16 split) + fused softmax/argmax partials ----
// 500 blocks x 64 cols; loop over 128 m-tiles (= steps, 32 batch rows each).
__global__ __launch_bounds__(256) void k_gemm(const int* __restrict__ inputs,
                                              const unsigned short* __restrict__ Ah,
                                              const unsigned short* __restrict__ Al,
                                              const unsigned short* __restrict__ Wph,
                                              const unsigned short* __restrict__ Wpl,
                                              const float* __restrict__ b_out,
                                              float* __restrict__ sp) {
    __shared__ float slds[B_][68];
    const int tid = threadIdx.x;
    const int w = tid >> 6, lane = tid & 63;
    const int vt = blockIdx.x * 4 + w;
    const int v0 = blockIdx.x * 64;
    const int c = lane & 15, kg = lane >> 4;
    const int bb = tid >> 3, sub = tid & 7;
    for (int mt = 0; mt < S_; ++mt) {
        f4 acc0 = {0.f, 0.f, 0.f, 0.f}, acc1 = {0.f, 0.f, 0.f, 0.f};
#pragma unroll 2
        for (int kc = 0; kc < 16; ++kc) {
            const size_t ab = ((((size_t)mt * 16 + kc) * 2) * 64 + lane) * 8;
            const size_t wb = (((size_t)vt * 16 + kc) * 64 + lane) * 8;
            bf8 A0h = *reinterpret_cast<const bf8*>(Ah + ab);
            bf8 A1h = *reinterpret_cast<const bf8*>(Ah + ab + 512);
            bf8 A0l = *reinterpret_cast<const bf8*>(Al + ab);
            bf8 A1l = *reinterpret_cast<const bf8*>(Al + ab + 512);
            bf8 Bh  = *reinterpret_cast<const bf8*>(Wph + wb);
            bf8 Bl  = *reinterpret_cast<const bf8*>(Wpl + wb);
            acc0 = __builtin_amdgcn_mfma_f32_16x16x32_bf16(A0h, Bh, acc0, 0, 0, 0);
            acc1 = __builtin_amdgcn_mfma_f32_16x16x32_bf16(A1h, Bh, acc1, 0, 0, 0);
            acc0 = __builtin_amdgcn_mfma_f32_16x16x32_bf16(A0l, Bh, acc0, 0, 0, 0);
            acc1 = __builtin_amdgcn_mfma_f32_16x16x32_bf16(A1l, Bh, acc1, 0, 0, 0);
            acc0 = __builtin_amdgcn_mfma_f32_16x16x32_bf16(A0h, Bl, acc0, 0, 0, 0);
            acc1 = __builtin_amdgcn_mfma_f32_16x16x32_bf16(A1h, Bl, acc1, 0, 0, 0);
        }
        __syncthreads();   // previous iteration's readers done
#pragma unroll
        for (int r = 0; r < 4; ++r) {
            slds[kg * 4 + r][w * 16 + c] = acc0[r];
            slds[16 + kg * 4 + r][w * 16 + c] = acc1[r];
        }
        __syncthreads();
        // fused online softmax / argmax / target over this block's 64 cols, 32 rows
        const int tok = inputs[bb * S_ + mt];
        float m = -INFINITY, s = 0.f, mv = -INFINITY, tv = -INFINITY;
        int mi = 0x7fffffff;
#pragma unroll
        for (int q = 0; q < 8; ++q) {
            const int vl = sub * 8 + q, v = v0 + vl;
            float x = slds[bb][vl] + b_out[v];
            float nm = fmaxf(m, x);
            s = s * __expf(m - nm) + __expf(x - nm);
            m = nm;
            if (x > mv) { mv = x; mi = v; }
            if (v == tok) tv = x;
        }
#pragma unroll
        for (int off = 1; off < 8; off <<= 1) {
            float cm = __shfl_xor(m, off), cs = __shfl_xor(s, off);
            float cmv = __shfl_xor(mv, off), ctv = __shfl_xor(tv, off);
            int cmi = __shfl_xor(mi, off);
            float nm = fmaxf(m, cm);
            s = s * __expf(m - nm) + cs * __expf(cm - nm);
            m = nm;
            if (cmv > mv || (cmv == mv && cmi < mi)) { mv = cmv; mi = cmi; }
            tv = fmaxf(tv, ctv);
        }
        if (sub == 0) {
            float* o = sp + ((size_t)(mt * 32 + bb) * NGB + blockIdx.x) * 5;
            o[0] = m; o[1] = s; o[2] = mv; o[3] = (float)mi; o[4] = tv;
        }
    }
}

// ---------------- merge 500 tile-partials per row -> symbols + per-row logp ---------
__global__ __launch_bounds__(256) void k_merge(const float* __restrict__ sp,
                                               float* __restrict__ out,
                                               float* __restrict__ lossbuf) {
    const int tid = threadIdx.x;
    const int mi16 = tid >> 4, l16 = tid & 15;
    const int m = blockIdx.x * 16 + mi16;
    float mm = -INFINITY, s = 0.f, mv = -INFINITY, tv = -INFINITY;
    int ai = 0x7fffffff;
    for (int i = l16; i < NGB; i += 16) {
        const float* o = sp + ((size_t)m * NGB + i) * 5;
        float cm = o[0], cs = o[1], cmv = o[2], ctv = o[4];
        int cmi = (int)o[3];
        float nm = fmaxf(mm, cm);
        s = s * expf(mm - nm) + cs * expf(cm - nm);
        mm = nm;
        if (cmv > mv || (cmv == mv && cmi < ai)) { mv = cmv; ai = cmi; }
        tv = fmaxf(tv, ctv);
    }
#pragma unroll
    for (int off = 1; off < 16; off <<= 1) {
        float cm = __shfl_xor(mm, off), cs = __shfl_xor(s, off);
        float cmv = __shfl_xor(mv, off), ctv = __shfl_xor(tv, off);
        int cmi = __shfl_xor(ai, off);
        float nm = fmaxf(mm, cm);
        s = s * expf(mm - nm) + cs * expf(cm - nm);
        mm = nm;
        if (cmv > mv || (cmv == mv && cmi < ai)) { mv = cmv; ai = cmi; }
        tv = fmaxf(tv, ctv);
    }
    if (l16 == 0) {
        const float logZ = mm + logf(s);
        const int t = m >> 5, b = m & 31;
        out[1 + b * S_ + t] = (float)ai;
        lossbuf[m] = tv - logZ;
    }
}

// ---------------- final: deterministic sum of per-row losses ----------------
__global__ __launch_bounds__(256) void k_sum(const float* __restrict__ lossbuf,
                                             float* __restrict__ out) {
    const int tid = threadIdx.x;
    float a = 0.f;
    for (int i = tid; i < B_ * S_; i += 256) a += lossbuf[i];
    __shared__ float red[256];
    red[tid] = a;
    __syncthreads();
    for (int off = 128; off > 0; off >>= 1) {
        if (tid < off) red[tid] += red[tid + off];
        __syncthreads();
    }
    if (tid == 0) out[0] = -red[0] / (float)B_;
}

extern "C" void kernel_launch(void* const* d_in, const int* in_sizes, int n_in,
                              void* d_out, int out_size, void* d_ws, size_t ws_size,
                              hipStream_t stream) {
    const int*   inputs = (const int*)d_in[0];
    const float* h0     = (const float*)d_in[3];
    const float* c0     = (const float*)d_in[4];
    const float* emb    = (const float*)d_in[5];
    const float* W_ih   = (const float*)d_in[6];
    const float* W_hh   = (const float*)d_in[7];
    const float* b_ih   = (const float*)d_in[8];
    const float* b_hh   = (const float*)d_in[9];
    const float* W_out  = (const float*)d_in[10];
    const float* b_out  = (const float*)d_in[11];
    float* out = (float*)d_out;

    char* p = (char*)d_ws;
    auto alloc = [&](size_t bytes) { char* r = p; p += (bytes + 255) & ~255ull; return r; };
    float* h        = (float*)alloc((size_t)B_ * H_ * 4);
    float* cst      = (float*)alloc((size_t)B_ * H_ * 4);
    float* lossbuf  = (float*)alloc((size_t)B_ * S_ * 4);
    float* gp       = (float*)alloc((size_t)KS_ * B_ * G4_ * 4);
    int*   bar      = (int*)alloc(1024);
    float* sp       = (float*)alloc((size_t)B_ * S_ * NGB * 5 * 4);      // 41 MB
    unsigned short* Ah  = (unsigned short*)alloc((size_t)S_ * 16 * 2 * 64 * 8 * 2);
    unsigned short* Al  = (unsigned short*)alloc((size_t)S_ * 16 * 2 * 64 * 8 * 2);
    unsigned short* Wph = (unsigned short*)alloc((size_t)NVT * 16 * 64 * 8 * 2);  // 32.8 MB
    unsigned short* Wpl = (unsigned short*)alloc((size_t)NVT * 16 * 64 * 8 * 2);
    float* XW       = (float*)alloc((size_t)S_ * B_ * G4_ * 4);          // 33.5 MB

    hipMemsetAsync(bar, 0, 1024, stream);
    k_wsplit<<<(NVT * 16 * 64) / 256, 256, 0, stream>>>(W_out, Wph, Wpl);
    k_xw<<<dim3(8, S_), 256, 0, stream>>>(inputs, emb, W_ih, b_ih, b_hh, XW);
    k_recur<<<NBLK_R, 256, 0, stream>>>(h0, c0, W_hh, XW, h, cst, Ah, Al, gp, bar);
    k_gemm<<<NGB, 256, 0, stream>>>(inputs, Ah, Al, Wph, Wpl, b_out, sp);
    k_merge<<<(B_ * S_) / 16, 256, 0, stream>>>(sp, out, lossbuf);
    k_sum<<<1, 256, 0, stream>>>(lossbuf, out);
}

// Round 6
// 3530.212 us; speedup vs baseline: 5.1860x; 1.9510x over previous
//
#include <hip/hip_runtime.h>
#include <math.h>

#define B_ 32
#define S_ 128
#define H_ 512
#define V_ 32000
#define G4_ 2048
#define NVT 2000        // W_out 16-col v-tiles
#define NGB 500         // gemm blocks (64 cols each)
#define RBLK 64         // recurrence blocks (n-chunks of 8)

typedef __attribute__((ext_vector_type(8))) short bf8;   // 8 x bf16 fragment
typedef __attribute__((ext_vector_type(4))) float f4;    // MFMA accumulator

__device__ __forceinline__ unsigned short f2bf(float x) {
    union { float f; unsigned u; } v; v.f = x;
    unsigned r = v.u + 0x7FFFu + ((v.u >> 16) & 1u);     // RNE
    return (unsigned short)(r >> 16);
}
__device__ __forceinline__ float bf2f(unsigned short b) {
    union { unsigned u; float f; } v; v.u = ((unsigned)b) << 16; return v.f;
}
__device__ __forceinline__ float4 ldf4(const float* p) {
    return *reinterpret_cast<const float4*>(p);
}

// ------ split W_out into bf16 hi/lo, pre-swizzled to MFMA B-fragment order (once) ----
__global__ __launch_bounds__(256) void k_wsplit(const float* __restrict__ W,
                                                unsigned short* __restrict__ Wph,
                                                unsigned short* __restrict__ Wpl) {
    const size_t id = (size_t)blockIdx.x * 256 + threadIdx.x;   // 0 .. NVT*16*64-1
    const int lane = (int)(id & 63);
    const size_t fc = id >> 6;            // vt*16 + kc
    const int kc = (int)(fc & 15);
    const size_t vt = fc >> 4;
    const size_t r = vt * 16 + (lane & 15);
    const int k0 = kc * 32 + (lane >> 4) * 8;
    const float* src = W + r * H_ + k0;
    bf8 hv, lv;
#pragma unroll
    for (int e = 0; e < 8; ++e) {
        float x = src[e];
        unsigned short hb = f2bf(x);
        hv[e] = (short)hb;
        lv[e] = (short)f2bf(x - bf2f(hb));
    }
    *reinterpret_cast<bf8*>(Wph + id * 8) = hv;
    *reinterpret_cast<bf8*>(Wpl + id * 8) = lv;
}

// ------ split W_hh into THREE bf16 levels, B-fragment order grouped per recur block ---
// jl within block g: jl = q*8 + nl -> row = q*512 + g*8 + nl; ntile = jl>>4.
__global__ __launch_bounds__(256) void k_whh3(const float* __restrict__ W,
                                              unsigned short* __restrict__ B1,
                                              unsigned short* __restrict__ B2,
                                              unsigned short* __restrict__ B3) {
    const size_t id = (size_t)blockIdx.x * 256 + threadIdx.x;  // ((g*2+nt)*16+kc)*64+lane
    const int lane = (int)(id & 63);
    const size_t fc = id >> 6;
    const int kc = (int)(fc & 15);
    const size_t gt = fc >> 4;
    const int nt = (int)(gt & 1);
    const int g = (int)(gt >> 1);
    const int c = lane & 15;
    const int q = nt * 2 + (c >> 3), nl = c & 7;
    const int row = q * 512 + g * 8 + nl;
    const int k0 = kc * 32 + (lane >> 4) * 8;
    const float* src = W + (size_t)row * H_ + k0;
    bf8 v1, v2, v3;
#pragma unroll
    for (int e = 0; e < 8; ++e) {
        float x = src[e];
        unsigned short a1 = f2bf(x);
        float r1 = x - bf2f(a1);
        unsigned short a2 = f2bf(r1);
        float r2 = r1 - bf2f(a2);
        v1[e] = (short)a1; v2[e] = (short)a2; v3[e] = (short)f2bf(r2);
    }
    *reinterpret_cast<bf8*>(B1 + id * 8) = v1;
    *reinterpret_cast<bf8*>(B2 + id * 8) = v2;
    *reinterpret_cast<bf8*>(B3 + id * 8) = v3;
}

// ------- precompute XW[t][b][j] = emb[tok[b,t]] @ W_ih^T + b_ih + b_hh (once) -------
__global__ __launch_bounds__(256) void k_xw(const int* __restrict__ inputs,
                                            const float* __restrict__ emb,
                                            const float* __restrict__ W_ih,
                                            const float* __restrict__ b_ih,
                                            const float* __restrict__ b_hh,
                                            float* __restrict__ XW) {
    __shared__ float es[16 * H_];
    const int tid = threadIdx.x;
    const int j = blockIdx.x * 256 + tid;
    const int t = blockIdx.y;
    const float bias = b_ih[j] + b_hh[j];
#pragma unroll
    for (int half = 0; half < 2; ++half) {
        __syncthreads();
        for (int idx = tid; idx < 16 * 128; idx += 256) {
            int b = idx >> 7, k4 = (idx & 127) << 2;
            int tok = inputs[(half * 16 + b) * S_ + t];
            *reinterpret_cast<float4*>(&es[b * H_ + k4]) = ldf4(emb + (size_t)tok * H_ + k4);
        }
        __syncthreads();
        float acc[16];
#pragma unroll
        for (int b = 0; b < 16; ++b) acc[b] = 0.f;
        for (int k = 0; k < H_; k += 4) {
            float4 wv = ldf4(W_ih + (size_t)j * H_ + k);
#pragma unroll
            for (int b = 0; b < 16; ++b) {
                float4 xv = *reinterpret_cast<const float4*>(&es[b * H_ + k]);
                acc[b] += wv.x * xv.x + wv.y * xv.y + wv.z * xv.z + wv.w * xv.w;
            }
        }
#pragma unroll
        for (int b = 0; b < 16; ++b)
            XW[(size_t)(t * B_ + half * 16 + b) * G4_ + j] = acc[b] + bias;
    }
}

// ---------------- the MFMA recurrence: 64 blocks, flag-sync, c in registers ----------
__global__ __launch_bounds__(256)
void k_recur(const float* __restrict__ h0, const float* __restrict__ c0,
             const unsigned short* __restrict__ B1f, const unsigned short* __restrict__ B2f,
             const unsigned short* __restrict__ B3f, const float* __restrict__ XW,
             unsigned short* __restrict__ A1, unsigned short* __restrict__ A2,
             unsigned short* __restrict__ A3, int* __restrict__ flags) {
    __shared__ unsigned short wl1[16384], wl2[16384], wl3[16384];   // 3 x 32 KB
    __shared__ float glds[32][33];                                  // gates exchange
    const int g = blockIdx.x, tid = threadIdx.x;

    // load this block's W_hh fragments into LDS (once)
    {
        const size_t base = (size_t)g * 16384;
        for (int i = tid; i < 2048; i += 256) {
            reinterpret_cast<uint4*>(wl1)[i] = reinterpret_cast<const uint4*>(B1f + base)[i];
            reinterpret_cast<uint4*>(wl2)[i] = reinterpret_cast<const uint4*>(B2f + base)[i];
            reinterpret_cast<uint4*>(wl3)[i] = reinterpret_cast<const uint4*>(B3f + base)[i];
        }
    }
    // cell-thread identity: (b, nl); n = g*8+nl owned forever (c stays in a register)
    const int b = tid >> 3, nl = tid & 7;
    const int n = g * 8 + nl;
    const int kc_w = g >> 2, kg_w = g & 3, half_w = b >> 4, lane_w = kg_w * 16 + (b & 15);
    float c_reg = c0[b * H_ + n];
    float hn = h0[b * H_ + n];

    auto write_frags = [&](int slot, int par, float h) {
        unsigned short a1 = f2bf(h);
        float r1 = h - bf2f(a1);
        unsigned short a2 = f2bf(r1);
        unsigned short a3 = f2bf(r1 - bf2f(a2));
        const size_t ix = ((((size_t)slot * 16 + kc_w) * 2 + half_w) * 64 + lane_w) * 8 + nl;
        A1[ix] = a1; A2[ix] = a2;
        const size_t ix3 = ((((size_t)par * 16 + kc_w) * 2 + half_w) * 64 + lane_w) * 8 + nl;
        A3[ix3] = a3;
    };
    write_frags(0, 0, hn);          // slot 0 = h_{-1} = h0
    __threadfence();
    __syncthreads();
    if (tid == 0)
        __hip_atomic_store(&flags[g * 32], 1, __ATOMIC_RELEASE, __HIP_MEMORY_SCOPE_AGENT);

    // wave roles for the MFMA phase
    const int wv = tid >> 6, lane = tid & 63;
    const int mt = wv >> 1, nt = wv & 1;
    const int cidx = lane & 15;

    for (int t = 0; t < S_; ++t) {
        // ---- wait for all blocks' h_{t-1} fragments ----
        if (tid < 64) {
            while (__hip_atomic_load(&flags[tid * 32], __ATOMIC_RELAXED,
                                     __HIP_MEMORY_SCOPE_AGENT) < t + 1)
                __builtin_amdgcn_s_sleep(1);
        }
        __threadfence();
        __syncthreads();
        // ---- 6-term MFMA gates: [32 x 512] x [512 x 32jl] ----
        const int par = t & 1;
        f4 acc = {0.f, 0.f, 0.f, 0.f};
        const unsigned short* a1p = A1 + ((((size_t)t * 16) * 2 + mt) * 64 + lane) * 8;
        const unsigned short* a2p = A2 + ((((size_t)t * 16) * 2 + mt) * 64 + lane) * 8;
        const unsigned short* a3p = A3 + ((((size_t)par * 16) * 2 + mt) * 64 + lane) * 8;
        const unsigned short* b1p = wl1 + ((size_t)(nt * 16) * 64 + lane) * 8;
        const unsigned short* b2p = wl2 + ((size_t)(nt * 16) * 64 + lane) * 8;
        const unsigned short* b3p = wl3 + ((size_t)(nt * 16) * 64 + lane) * 8;
#pragma unroll 4
        for (int kc = 0; kc < 16; ++kc) {
            bf8 A1v = *reinterpret_cast<const bf8*>(a1p + (size_t)kc * 1024);
            bf8 A2v = *reinterpret_cast<const bf8*>(a2p + (size_t)kc * 1024);
            bf8 A3v = *reinterpret_cast<const bf8*>(a3p + (size_t)kc * 1024);
            bf8 B1v = *reinterpret_cast<const bf8*>(b1p + (size_t)kc * 512);
            bf8 B2v = *reinterpret_cast<const bf8*>(b2p + (size_t)kc * 512);
            bf8 B3v = *reinterpret_cast<const bf8*>(b3p + (size_t)kc * 512);
            acc = __builtin_amdgcn_mfma_f32_16x16x32_bf16(A1v, B1v, acc, 0, 0, 0);
            acc = __builtin_amdgcn_mfma_f32_16x16x32_bf16(A1v, B2v, acc, 0, 0, 0);
            acc = __builtin_amdgcn_mfma_f32_16x16x32_bf16(A2v, B1v, acc, 0, 0, 0);
            acc = __builtin_amdgcn_mfma_f32_16x16x32_bf16(A2v, B2v, acc, 0, 0, 0);
            acc = __builtin_amdgcn_mfma_f32_16x16x32_bf16(A1v, B3v, acc, 0, 0, 0);
            acc = __builtin_amdgcn_mfma_f32_16x16x32_bf16(A3v, B1v, acc, 0, 0, 0);
        }
        // ---- stage gates to LDS: C layout col=lane&15 (jl), row=(lane>>4)*4+r (b) ----
#pragma unroll
        for (int r = 0; r < 4; ++r)
            glds[mt * 16 + (lane >> 4) * 4 + r][nt * 16 + cidx] = acc[r];
        __syncthreads();
        // ---- cell: activations + state update (c in register) ----
        const float* xwp = XW + ((size_t)t * B_ + b) * G4_;
        const float s_i = glds[b][nl]      + xwp[0 * 512 + n];
        const float s_f = glds[b][8 + nl]  + xwp[1 * 512 + n];
        const float s_g = glds[b][16 + nl] + xwp[2 * 512 + n];
        const float s_o = glds[b][24 + nl] + xwp[3 * 512 + n];
        const float ig = 1.f / (1.f + expf(-s_i));
        const float fg = 1.f / (1.f + expf(-s_f));
        const float gg = tanhf(s_g);
        const float og = 1.f / (1.f + expf(-s_o));
        c_reg = fg * c_reg + ig * gg;
        hn = og * tanhf(c_reg);
        write_frags(t + 1, par ^ 1, hn);
        __threadfence();
        __syncthreads();
        if (tid == 0)
            __hip_atomic_store(&flags[g * 32], t + 2, __ATOMIC_RELEASE,
                               __HIP_MEMORY_SCOPE_AGENT);
    }
}

// ------- batched logits GEMM (3-term bf16 split) + fused softmax/argmax partials ----
__global__ __launch_bounds__(256) void k_gemm(const int* __restrict__ inputs,
                                              const unsigned short* __restrict__ Ah,
                                              const unsigned short* __restrict__ Al,
                                              const unsigned short* __restrict__ Wph,
                                              const unsigned short* __restrict__ Wpl,
                                              const float* __restrict__ b_out,
                                              float* __restrict__ sp) {
    __shared__ float slds[B_][68];
    const int tid = threadIdx.x;
    const int w = tid >> 6, lane = tid & 63;
    const int vt = blockIdx.x * 4 + w;
    const int v0 = blockIdx.x * 64;
    const int c = lane & 15, kg = lane >> 4;
    const int bb = tid >> 3, sub = tid & 7;
    for (int mt = 0; mt < S_; ++mt) {
        f4 acc0 = {0.f, 0.f, 0.f, 0.f}, acc1 = {0.f, 0.f, 0.f, 0.f};
#pragma unroll 2
        for (int kc = 0; kc < 16; ++kc) {
            const size_t ab = ((((size_t)(mt + 1) * 16 + kc) * 2) * 64 + lane) * 8;
            const size_t wb = (((size_t)vt * 16 + kc) * 64 + lane) * 8;
            bf8 A0h = *reinterpret_cast<const bf8*>(Ah + ab);
            bf8 A1h = *reinterpret_cast<const bf8*>(Ah + ab + 512);
            bf8 A0l = *reinterpret_cast<const bf8*>(Al + ab);
            bf8 A1l = *reinterpret_cast<const bf8*>(Al + ab + 512);
            bf8 Bh  = *reinterpret_cast<const bf8*>(Wph + wb);
            bf8 Bl  = *reinterpret_cast<const bf8*>(Wpl + wb);
            acc0 = __builtin_amdgcn_mfma_f32_16x16x32_bf16(A0h, Bh, acc0, 0, 0, 0);
            acc1 = __builtin_amdgcn_mfma_f32_16x16x32_bf16(A1h, Bh, acc1, 0, 0, 0);
            acc0 = __builtin_amdgcn_mfma_f32_16x16x32_bf16(A0l, Bh, acc0, 0, 0, 0);
            acc1 = __builtin_amdgcn_mfma_f32_16x16x32_bf16(A1l, Bh, acc1, 0, 0, 0);
            acc0 = __builtin_amdgcn_mfma_f32_16x16x32_bf16(A0h, Bl, acc0, 0, 0, 0);
            acc1 = __builtin_amdgcn_mfma_f32_16x16x32_bf16(A1h, Bl, acc1, 0, 0, 0);
        }
        __syncthreads();   // previous iteration's readers done
#pragma unroll
        for (int r = 0; r < 4; ++r) {
            slds[kg * 4 + r][w * 16 + c] = acc0[r];
            slds[16 + kg * 4 + r][w * 16 + c] = acc1[r];
        }
        __syncthreads();
        const int tok = inputs[bb * S_ + mt];
        float m = -INFINITY, s = 0.f, mv = -INFINITY, tv = -INFINITY;
        int mi = 0x7fffffff;
#pragma unroll
        for (int q = 0; q < 8; ++q) {
            const int vl = sub * 8 + q, v = v0 + vl;
            float x = slds[bb][vl] + b_out[v];
            float nm = fmaxf(m, x);
            s = s * __expf(m - nm) + __expf(x - nm);
            m = nm;
            if (x > mv) { mv = x; mi = v; }
            if (v == tok) tv = x;
        }
#pragma unroll
        for (int off = 1; off < 8; off <<= 1) {
            float cm = __shfl_xor(m, off), cs = __shfl_xor(s, off);
            float cmv = __shfl_xor(mv, off), ctv = __shfl_xor(tv, off);
            int cmi = __shfl_xor(mi, off);
            float nm = fmaxf(m, cm);
            s = s * __expf(m - nm) + cs * __expf(cm - nm);
            m = nm;
            if (cmv > mv || (cmv == mv && cmi < mi)) { mv = cmv; mi = cmi; }
            tv = fmaxf(tv, ctv);
        }
        if (sub == 0) {
            float* o = sp + ((size_t)(mt * 32 + bb) * NGB + blockIdx.x) * 5;
            o[0] = m; o[1] = s; o[2] = mv; o[3] = (float)mi; o[4] = tv;
        }
    }
}

// ---------------- merge 500 tile-partials per row -> symbols + per-row logp ---------
__global__ __launch_bounds__(256) void k_merge(const float* __restrict__ sp,
                                               float* __restrict__ out,
                                               float* __restrict__ lossbuf) {
    const int tid = threadIdx.x;
    const int mi16 = tid >> 4, l16 = tid & 15;
    const int m = blockIdx.x * 16 + mi16;
    float mm = -INFINITY, s = 0.f, mv = -INFINITY, tv = -INFINITY;
    int ai = 0x7fffffff;
    for (int i = l16; i < NGB; i += 16) {
        const float* o = sp + ((size_t)m * NGB + i) * 5;
        float cm = o[0], cs = o[1], cmv = o[2], ctv = o[4];
        int cmi = (int)o[3];
        float nm = fmaxf(mm, cm);
        s = s * expf(mm - nm) + cs * expf(cm - nm);
        mm = nm;
        if (cmv > mv || (cmv == mv && cmi < ai)) { mv = cmv; ai = cmi; }
        tv = fmaxf(tv, ctv);
    }
#pragma unroll
    for (int off = 1; off < 16; off <<= 1) {
        float cm = __shfl_xor(mm, off), cs = __shfl_xor(s, off);
        float cmv = __shfl_xor(mv, off), ctv = __shfl_xor(tv, off);
        int cmi = __shfl_xor(ai, off);
        float nm = fmaxf(mm, cm);
        s = s * expf(mm - nm) + cs * expf(cm - nm);
        mm = nm;
        if (cmv > mv || (cmv == mv && cmi < ai)) { mv = cmv; ai = cmi; }
        tv = fmaxf(tv, ctv);
    }
    if (l16 == 0) {
        const float logZ = mm + logf(s);
        const int t = m >> 5, b = m & 31;
        out[1 + b * S_ + t] = (float)ai;
        lossbuf[m] = tv - logZ;
    }
}

// ---------------- final: deterministic sum of per-row losses ----------------
__global__ __launch_bounds__(256) void k_sum(const float* __restrict__ lossbuf,
                                             float* __restrict__ out) {
    const int tid = threadIdx.x;
    float a = 0.f;
    for (int i = tid; i < B_ * S_; i += 256) a += lossbuf[i];
    __shared__ float red[256];
    red[tid] = a;
    __syncthreads();
    for (int off = 128; off > 0; off >>= 1) {
        if (tid < off) red[tid] += red[tid + off];
        __syncthreads();
    }
    if (tid == 0) out[0] = -red[0] / (float)B_;
}

extern "C" void kernel_launch(void* const* d_in, const int* in_sizes, int n_in,
                              void* d_out, int out_size, void* d_ws, size_t ws_size,
                              hipStream_t stream) {
    const int*   inputs = (const int*)d_in[0];
    const float* h0     = (const float*)d_in[3];
    const float* c0     = (const float*)d_in[4];
    const float* emb    = (const float*)d_in[5];
    const float* W_ih   = (const float*)d_in[6];
    const float* W_hh   = (const float*)d_in[7];
    const float* b_ih   = (const float*)d_in[8];
    const float* b_hh   = (const float*)d_in[9];
    const float* W_out  = (const float*)d_in[10];
    const float* b_out  = (const float*)d_in[11];
    float* out = (float*)d_out;

    char* p = (char*)d_ws;
    auto alloc = [&](size_t bytes) { char* r = p; p += (bytes + 255) & ~255ull; return r; };
    float* lossbuf  = (float*)alloc((size_t)B_ * S_ * 4);
    int*   flags    = (int*)alloc(64 * 32 * 4);
    float* sp       = (float*)alloc((size_t)B_ * S_ * NGB * 5 * 4);          // 41 MB
    unsigned short* A1  = (unsigned short*)alloc((size_t)(S_ + 1) * 16384 * 2);
    unsigned short* A2  = (unsigned short*)alloc((size_t)(S_ + 1) * 16384 * 2);
    unsigned short* A3  = (unsigned short*)alloc((size_t)2 * 16384 * 2);
    unsigned short* Wph = (unsigned short*)alloc((size_t)NVT * 16 * 64 * 8 * 2);  // 32.8 MB
    unsigned short* Wpl = (unsigned short*)alloc((size_t)NVT * 16 * 64 * 8 * 2);
    unsigned short* B1f = (unsigned short*)alloc((size_t)RBLK * 16384 * 2);   // 2.1 MB
    unsigned short* B2f = (unsigned short*)alloc((size_t)RBLK * 16384 * 2);
    unsigned short* B3f = (unsigned short*)alloc((size_t)RBLK * 16384 * 2);
    float* XW       = (float*)alloc((size_t)S_ * B_ * G4_ * 4);               // 33.5 MB

    hipMemsetAsync(flags, 0, 64 * 32 * 4, stream);
    k_wsplit<<<(NVT * 16 * 64) / 256, 256, 0, stream>>>(W_out, Wph, Wpl);
    k_whh3<<<(RBLK * 2 * 16 * 64) / 256, 256, 0, stream>>>(W_hh, B1f, B2f, B3f);
    k_xw<<<dim3(8, S_), 256, 0, stream>>>(inputs, emb, W_ih, b_ih, b_hh, XW);
    k_recur<<<RBLK, 256, 0, stream>>>(h0, c0, B1f, B2f, B3f, XW, A1, A2, A3, flags);
    k_gemm<<<NGB, 256, 0, stream>>>(inputs, A1, A2, Wph, Wpl, b_out, sp);
    k_merge<<<(B_ * S_) / 16, 256, 0, stream>>>(sp, out, lossbuf);
    k_sum<<<1, 256, 0, stream>>>(lossbuf, out);
}

// Round 7
// 2921.392 us; speedup vs baseline: 6.2667x; 1.2084x over previous
//
#include <hip/hip_runtime.h>
#include <math.h>

#define B_ 32
#define S_ 128
#define H_ 512
#define V_ 32000
#define G4_ 2048
#define NVT 2000        // W_out 16-col v-tiles
#define NGB 500         // gemm blocks (64 cols each)
#define RBLK 64         // recurrence blocks (n-chunks of 8)

typedef __attribute__((ext_vector_type(8))) short bf8;   // 8 x bf16 fragment
typedef __attribute__((ext_vector_type(4))) float f4;    // MFMA accumulator

__device__ __forceinline__ unsigned short f2bf(float x) {
    union { float f; unsigned u; } v; v.f = x;
    unsigned r = v.u + 0x7FFFu + ((v.u >> 16) & 1u);     // RNE
    return (unsigned short)(r >> 16);
}
__device__ __forceinline__ float bf2f(unsigned short b) {
    union { unsigned u; float f; } v; v.u = ((unsigned)b) << 16; return v.f;
}
__device__ __forceinline__ float4 ldf4(const float* p) {
    return *reinterpret_cast<const float4*>(p);
}
__device__ __forceinline__ void gload_lds16(const void* g, void* l) {
    __builtin_amdgcn_global_load_lds((const __attribute__((address_space(1))) unsigned*)g,
                                     (__attribute__((address_space(3))) unsigned*)l, 16, 0, 0);
}

// ------ split W_out into bf16 hi/lo, pre-swizzled to MFMA B-fragment order (once) ----
__global__ __launch_bounds__(256) void k_wsplit(const float* __restrict__ W,
                                                unsigned short* __restrict__ Wph,
                                                unsigned short* __restrict__ Wpl) {
    const size_t id = (size_t)blockIdx.x * 256 + threadIdx.x;   // 0 .. NVT*16*64-1
    const int lane = (int)(id & 63);
    const size_t fc = id >> 6;            // vt*16 + kc
    const int kc = (int)(fc & 15);
    const size_t vt = fc >> 4;
    const size_t r = vt * 16 + (lane & 15);
    const int k0 = kc * 32 + (lane >> 4) * 8;
    const float* src = W + r * H_ + k0;
    bf8 hv, lv;
#pragma unroll
    for (int e = 0; e < 8; ++e) {
        float x = src[e];
        unsigned short hb = f2bf(x);
        hv[e] = (short)hb;
        lv[e] = (short)f2bf(x - bf2f(hb));
    }
    *reinterpret_cast<bf8*>(Wph + id * 8) = hv;
    *reinterpret_cast<bf8*>(Wpl + id * 8) = lv;
}

// ------ split W_hh into THREE bf16 levels, B-fragment order grouped per recur block ---
__global__ __launch_bounds__(256) void k_whh3(const float* __restrict__ W,
                                              unsigned short* __restrict__ B1,
                                              unsigned short* __restrict__ B2,
                                              unsigned short* __restrict__ B3) {
    const size_t id = (size_t)blockIdx.x * 256 + threadIdx.x;  // ((g*2+nt)*16+kc)*64+lane
    const int lane = (int)(id & 63);
    const size_t fc = id >> 6;
    const int kc = (int)(fc & 15);
    const size_t gt = fc >> 4;
    const int nt = (int)(gt & 1);
    const int g = (int)(gt >> 1);
    const int c = lane & 15;
    const int q = nt * 2 + (c >> 3), nl = c & 7;
    const int row = q * 512 + g * 8 + nl;
    const int k0 = kc * 32 + (lane >> 4) * 8;
    const float* src = W + (size_t)row * H_ + k0;
    bf8 v1, v2, v3;
#pragma unroll
    for (int e = 0; e < 8; ++e) {
        float x = src[e];
        unsigned short a1 = f2bf(x);
        float r1 = x - bf2f(a1);
        unsigned short a2 = f2bf(r1);
        float r2 = r1 - bf2f(a2);
        v1[e] = (short)a1; v2[e] = (short)a2; v3[e] = (short)f2bf(r2);
    }
    *reinterpret_cast<bf8*>(B1 + id * 8) = v1;
    *reinterpret_cast<bf8*>(B2 + id * 8) = v2;
    *reinterpret_cast<bf8*>(B3 + id * 8) = v3;
}

// ------- precompute XW[t][b][j] = emb[tok[b,t]] @ W_ih^T + b_ih + b_hh (once) -------
__global__ __launch_bounds__(256) void k_xw(const int* __restrict__ inputs,
                                            const float* __restrict__ emb,
                                            const float* __restrict__ W_ih,
                                            const float* __restrict__ b_ih,
                                            const float* __restrict__ b_hh,
                                            float* __restrict__ XW) {
    __shared__ float es[16 * H_];
    const int tid = threadIdx.x;
    const int j = blockIdx.x * 256 + tid;
    const int t = blockIdx.y;
    const float bias = b_ih[j] + b_hh[j];
#pragma unroll
    for (int half = 0; half < 2; ++half) {
        __syncthreads();
        for (int idx = tid; idx < 16 * 128; idx += 256) {
            int b = idx >> 7, k4 = (idx & 127) << 2;
            int tok = inputs[(half * 16 + b) * S_ + t];
            *reinterpret_cast<float4*>(&es[b * H_ + k4]) = ldf4(emb + (size_t)tok * H_ + k4);
        }
        __syncthreads();
        float acc[16];
#pragma unroll
        for (int b = 0; b < 16; ++b) acc[b] = 0.f;
        for (int k = 0; k < H_; k += 4) {
            float4 wv = ldf4(W_ih + (size_t)j * H_ + k);
#pragma unroll
            for (int b = 0; b < 16; ++b) {
                float4 xv = *reinterpret_cast<const float4*>(&es[b * H_ + k]);
                acc[b] += wv.x * xv.x + wv.y * xv.y + wv.z * xv.z + wv.w * xv.w;
            }
        }
#pragma unroll
        for (int b = 0; b < 16; ++b)
            XW[(size_t)(t * B_ + half * 16 + b) * G4_ + j] = acc[b] + bias;
    }
}

// ---------------- the MFMA recurrence: 64 blocks, fence-free flag sync ----------------
__global__ __launch_bounds__(256)
void k_recur(const float* __restrict__ h0, const float* __restrict__ c0,
             const unsigned short* __restrict__ B1f, const unsigned short* __restrict__ B2f,
             const unsigned short* __restrict__ B3f, const float* __restrict__ XW,
             unsigned short* __restrict__ A1, unsigned short* __restrict__ A2,
             unsigned short* __restrict__ A3, int* __restrict__ flags) {
    __shared__ unsigned short wl1[16384], wl2[16384], wl3[16384];   // 3 x 32 KB
    __shared__ float glds[32][33];                                  // gates exchange
    const int g = blockIdx.x, tid = threadIdx.x;

    // load this block's W_hh fragments into LDS (once)
    {
        const size_t base = (size_t)g * 16384;
        for (int i = tid; i < 2048; i += 256) {
            reinterpret_cast<uint4*>(wl1)[i] = reinterpret_cast<const uint4*>(B1f + base)[i];
            reinterpret_cast<uint4*>(wl2)[i] = reinterpret_cast<const uint4*>(B2f + base)[i];
            reinterpret_cast<uint4*>(wl3)[i] = reinterpret_cast<const uint4*>(B3f + base)[i];
        }
    }
    // cell-thread identity: (b, nl); n = g*8+nl owned forever (c stays in a register)
    const int b = tid >> 3, nl = tid & 7;
    const int n = g * 8 + nl;
    const int kc_w = g >> 2, kg_w = g & 3, half_w = b >> 4, lane_w = kg_w * 16 + (b & 15);
    float c_reg = c0[b * H_ + n];
    float hn = h0[b * H_ + n];

    // publish h fragments: packed u32 relaxed agent-scope atomic stores (write-through
    // to L3, no fences, no dirty L2 lines left behind)
    auto write_frags = [&](int slot, float h) {
        unsigned short a1 = f2bf(h);
        float r1 = h - bf2f(a1);
        unsigned short a2 = f2bf(r1);
        unsigned short a3 = f2bf(r1 - bf2f(a2));
        unsigned v1 = a1, v2 = a2, v3 = a3;
        unsigned q1 = (unsigned)__shfl_xor((int)v1, 1);
        unsigned q2 = (unsigned)__shfl_xor((int)v2, 1);
        unsigned q3 = (unsigned)__shfl_xor((int)v3, 1);
        if ((nl & 1) == 0) {
            const size_t ix = ((((size_t)slot * 16 + kc_w) * 2 + half_w) * 64 + lane_w) * 8 + nl;
            __hip_atomic_store((unsigned*)(A1 + ix), v1 | (q1 << 16),
                               __ATOMIC_RELAXED, __HIP_MEMORY_SCOPE_AGENT);
            __hip_atomic_store((unsigned*)(A2 + ix), v2 | (q2 << 16),
                               __ATOMIC_RELAXED, __HIP_MEMORY_SCOPE_AGENT);
            __hip_atomic_store((unsigned*)(A3 + ix), v3 | (q3 << 16),
                               __ATOMIC_RELAXED, __HIP_MEMORY_SCOPE_AGENT);
        }
    };
    write_frags(0, hn);          // slot 0 = h_{-1} = h0
    asm volatile("s_waitcnt vmcnt(0)" ::: "memory");   // stores acked at L3
    __syncthreads();
    if (tid == 0)
        __hip_atomic_store(&flags[g * 32], 1, __ATOMIC_RELAXED, __HIP_MEMORY_SCOPE_AGENT);

    // wave roles for the MFMA phase
    const int wv = tid >> 6, lane = tid & 63;
    const int mt = wv >> 1, nt = wv & 1;
    const int cidx = lane & 15;

    for (int t = 0; t < S_; ++t) {
        // ---- wait for all blocks' h_{t-1} fragments (flag implies data at L3) ----
        if (tid < 64) {
            while (__hip_atomic_load(&flags[tid * 32], __ATOMIC_RELAXED,
                                     __HIP_MEMORY_SCOPE_AGENT) < t + 1)
                __builtin_amdgcn_s_sleep(1);
        }
        __syncthreads();
        // ---- 6-term MFMA gates: [32 x 512] x [512 x 32jl] (plain loads: slot t is
        //      a fresh address range, reader caches cannot hold stale copies) ----
        f4 acc = {0.f, 0.f, 0.f, 0.f};
        const unsigned short* a1p = A1 + ((((size_t)t * 16) * 2 + mt) * 64 + lane) * 8;
        const unsigned short* a2p = A2 + ((((size_t)t * 16) * 2 + mt) * 64 + lane) * 8;
        const unsigned short* a3p = A3 + ((((size_t)t * 16) * 2 + mt) * 64 + lane) * 8;
        const unsigned short* b1p = wl1 + ((size_t)(nt * 16) * 64 + lane) * 8;
        const unsigned short* b2p = wl2 + ((size_t)(nt * 16) * 64 + lane) * 8;
        const unsigned short* b3p = wl3 + ((size_t)(nt * 16) * 64 + lane) * 8;
#pragma unroll 4
        for (int kc = 0; kc < 16; ++kc) {
            bf8 A1v = *reinterpret_cast<const bf8*>(a1p + (size_t)kc * 1024);
            bf8 A2v = *reinterpret_cast<const bf8*>(a2p + (size_t)kc * 1024);
            bf8 A3v = *reinterpret_cast<const bf8*>(a3p + (size_t)kc * 1024);
            bf8 B1v = *reinterpret_cast<const bf8*>(b1p + (size_t)kc * 512);
            bf8 B2v = *reinterpret_cast<const bf8*>(b2p + (size_t)kc * 512);
            bf8 B3v = *reinterpret_cast<const bf8*>(b3p + (size_t)kc * 512);
            acc = __builtin_amdgcn_mfma_f32_16x16x32_bf16(A1v, B1v, acc, 0, 0, 0);
            acc = __builtin_amdgcn_mfma_f32_16x16x32_bf16(A1v, B2v, acc, 0, 0, 0);
            acc = __builtin_amdgcn_mfma_f32_16x16x32_bf16(A2v, B1v, acc, 0, 0, 0);
            acc = __builtin_amdgcn_mfma_f32_16x16x32_bf16(A2v, B2v, acc, 0, 0, 0);
            acc = __builtin_amdgcn_mfma_f32_16x16x32_bf16(A1v, B3v, acc, 0, 0, 0);
            acc = __builtin_amdgcn_mfma_f32_16x16x32_bf16(A3v, B1v, acc, 0, 0, 0);
        }
        // ---- stage gates to LDS: C layout col=lane&15 (jl), row=(lane>>4)*4+r (b) ----
#pragma unroll
        for (int r = 0; r < 4; ++r)
            glds[mt * 16 + (lane >> 4) * 4 + r][nt * 16 + cidx] = acc[r];
        __syncthreads();
        // ---- cell: activations + state update (c in register) ----
        const float* xwp = XW + ((size_t)t * B_ + b) * G4_;
        const float s_i = glds[b][nl]      + xwp[0 * 512 + n];
        const float s_f = glds[b][8 + nl]  + xwp[1 * 512 + n];
        const float s_g = glds[b][16 + nl] + xwp[2 * 512 + n];
        const float s_o = glds[b][24 + nl] + xwp[3 * 512 + n];
        const float ig = 1.f / (1.f + expf(-s_i));
        const float fg = 1.f / (1.f + expf(-s_f));
        const float gg = tanhf(s_g);
        const float og = 1.f / (1.f + expf(-s_o));
        c_reg = fg * c_reg + ig * gg;
        hn = og * tanhf(c_reg);
        write_frags(t + 1, hn);
        asm volatile("s_waitcnt vmcnt(0)" ::: "memory");   // h_t fragments at L3
        __syncthreads();
        if (tid == 0)
            __hip_atomic_store(&flags[g * 32], t + 2, __ATOMIC_RELAXED,
                               __HIP_MEMORY_SCOPE_AGENT);
    }
}

// ------- batched logits GEMM (3-term bf16 split), LDS-staged A (double-buffered) ----
__global__ __launch_bounds__(256) void k_gemm(const int* __restrict__ inputs,
                                              const unsigned short* __restrict__ Ah,
                                              const unsigned short* __restrict__ Al,
                                              const unsigned short* __restrict__ Wph,
                                              const unsigned short* __restrict__ Wpl,
                                              const float* __restrict__ b_out,
                                              float* __restrict__ sp) {
    __shared__ unsigned short abuf[2][32768];   // [buf][A1: 0..16383 | A2: 16384..32767]
    __shared__ float slds[B_][68];
    const int tid = threadIdx.x;
    const int w = tid >> 6, lane = tid & 63;
    const int vt = blockIdx.x * 4 + w;
    const int v0 = blockIdx.x * 64;
    const int c = lane & 15, kg = lane >> 4;
    const int bb = tid >> 3, sub = tid & 7;

    auto stage = [&](int slot, int buf) {   // copy A1[slot]+A2[slot] (64 KB) into abuf[buf]
        const unsigned short* s1 = Ah + (size_t)slot * 16384;
        const unsigned short* s2 = Al + (size_t)slot * 16384;
        for (int ch = w; ch < 64; ch += 4) {            // 1 KB chunks, identity layout
            const unsigned short* src =
                (ch < 32 ? s1 + ch * 512 : s2 + (ch - 32) * 512) + lane * 8;
            gload_lds16(src, &abuf[buf][ch * 512]);     // wave-uniform LDS base
        }
    };

    stage(1, 0);
    asm volatile("s_waitcnt vmcnt(0)" ::: "memory");
    __builtin_amdgcn_s_barrier();

    for (int mt = 0; mt < S_; ++mt) {
        const int buf = mt & 1;
        if (mt + 1 < S_) stage(mt + 2, buf ^ 1);        // async prefetch into other buffer
        f4 acc0 = {0.f, 0.f, 0.f, 0.f}, acc1 = {0.f, 0.f, 0.f, 0.f};
#pragma unroll 4
        for (int kc = 0; kc < 16; ++kc) {
            const int o0 = ((kc * 2 + 0) * 64 + lane) * 8;
            const int o1 = ((kc * 2 + 1) * 64 + lane) * 8;
            const size_t wb = (((size_t)vt * 16 + kc) * 64 + lane) * 8;
            bf8 A0h = *reinterpret_cast<const bf8*>(&abuf[buf][o0]);
            bf8 A1h = *reinterpret_cast<const bf8*>(&abuf[buf][o1]);
            bf8 A0l = *reinterpret_cast<const bf8*>(&abuf[buf][16384 + o0]);
            bf8 A1l = *reinterpret_cast<const bf8*>(&abuf[buf][16384 + o1]);
            bf8 Bh  = *reinterpret_cast<const bf8*>(Wph + wb);
            bf8 Bl  = *reinterpret_cast<const bf8*>(Wpl + wb);
            acc0 = __builtin_amdgcn_mfma_f32_16x16x32_bf16(A0h, Bh, acc0, 0, 0, 0);
            acc1 = __builtin_amdgcn_mfma_f32_16x16x32_bf16(A1h, Bh, acc1, 0, 0, 0);
            acc0 = __builtin_amdgcn_mfma_f32_16x16x32_bf16(A0l, Bh, acc0, 0, 0, 0);
            acc1 = __builtin_amdgcn_mfma_f32_16x16x32_bf16(A1l, Bh, acc1, 0, 0, 0);
            acc0 = __builtin_amdgcn_mfma_f32_16x16x32_bf16(A0h, Bl, acc0, 0, 0, 0);
            acc1 = __builtin_amdgcn_mfma_f32_16x16x32_bf16(A1h, Bl, acc1, 0, 0, 0);
        }
        __builtin_amdgcn_s_barrier();                   // prev epilogue's slds reads done
#pragma unroll
        for (int r = 0; r < 4; ++r) {
            slds[kg * 4 + r][w * 16 + c] = acc0[r];
            slds[16 + kg * 4 + r][w * 16 + c] = acc1[r];
        }
        asm volatile("s_waitcnt lgkmcnt(0)" ::: "memory");
        __builtin_amdgcn_s_barrier();
        const int tok = inputs[bb * S_ + mt];
        float m = -INFINITY, s = 0.f, mv = -INFINITY, tv = -INFINITY;
        int mi = 0x7fffffff;
#pragma unroll
        for (int q = 0; q < 8; ++q) {
            const int vl = sub * 8 + q, v = v0 + vl;
            float x = slds[bb][vl] + b_out[v];
            float nm = fmaxf(m, x);
            s = s * __expf(m - nm) + __expf(x - nm);
            m = nm;
            if (x > mv) { mv = x; mi = v; }
            if (v == tok) tv = x;
        }
#pragma unroll
        for (int off = 1; off < 8; off <<= 1) {
            float cm = __shfl_xor(m, off), cs = __shfl_xor(s, off);
            float cmv = __shfl_xor(mv, off), ctv = __shfl_xor(tv, off);
            int cmi = __shfl_xor(mi, off);
            float nm = fmaxf(m, cm);
            s = s * __expf(m - nm) + cs * __expf(cm - nm);
            m = nm;
            if (cmv > mv || (cmv == mv && cmi < mi)) { mv = cmv; mi = cmi; }
            tv = fmaxf(tv, ctv);
        }
        if (sub == 0) {
            float* o = sp + ((size_t)(mt * 32 + bb) * NGB + blockIdx.x) * 5;
            o[0] = m; o[1] = s; o[2] = mv; o[3] = (float)mi; o[4] = tv;
        }
        asm volatile("s_waitcnt vmcnt(0)" ::: "memory");   // this wave's stage loads done
        __builtin_amdgcn_s_barrier();                      // all waves' chunks in LDS
    }
}

// ---------------- merge 500 tile-partials per row -> symbols + per-row logp ---------
__global__ __launch_bounds__(256) void k_merge(const float* __restrict__ sp,
                                               float* __restrict__ out,
                                               float* __restrict__ lossbuf) {
    const int tid = threadIdx.x;
    const int mi16 = tid >> 4, l16 = tid & 15;
    const int m = blockIdx.x * 16 + mi16;
    float mm = -INFINITY, s = 0.f, mv = -INFINITY, tv = -INFINITY;
    int ai = 0x7fffffff;
    for (int i = l16; i < NGB; i += 16) {
        const float* o = sp + ((size_t)m * NGB + i) * 5;
        float cm = o[0], cs = o[1], cmv = o[2], ctv = o[4];
        int cmi = (int)o[3];
        float nm = fmaxf(mm, cm);
        s = s * expf(mm - nm) + cs * expf(cm - nm);
        mm = nm;
        if (cmv > mv || (cmv == mv && cmi < ai)) { mv = cmv; ai = cmi; }
        tv = fmaxf(tv, ctv);
    }
#pragma unroll
    for (int off = 1; off < 16; off <<= 1) {
        float cm = __shfl_xor(mm, off), cs = __shfl_xor(s, off);
        float cmv = __shfl_xor(mv, off), ctv = __shfl_xor(tv, off);
        int cmi = __shfl_xor(ai, off);
        float nm = fmaxf(mm, cm);
        s = s * expf(mm - nm) + cs * expf(cm - nm);
        mm = nm;
        if (cmv > mv || (cmv == mv && cmi < ai)) { mv = cmv; ai = cmi; }
        tv = fmaxf(tv, ctv);
    }
    if (l16 == 0) {
        const float logZ = mm + logf(s);
        const int t = m >> 5, b = m & 31;
        out[1 + b * S_ + t] = (float)ai;
        lossbuf[m] = tv - logZ;
    }
}

// ---------------- final: deterministic sum of per-row losses ----------------
__global__ __launch_bounds__(256) void k_sum(const float* __restrict__ lossbuf,
                                             float* __restrict__ out) {
    const int tid = threadIdx.x;
    float a = 0.f;
    for (int i = tid; i < B_ * S_; i += 256) a += lossbuf[i];
    __shared__ float red[256];
    red[tid] = a;
    __syncthreads();
    for (int off = 128; off > 0; off >>= 1) {
        if (tid < off) red[tid] += red[tid + off];
        __syncthreads();
    }
    if (tid == 0) out[0] = -red[0] / (float)B_;
}

extern "C" void kernel_launch(void* const* d_in, const int* in_sizes, int n_in,
                              void* d_out, int out_size, void* d_ws, size_t ws_size,
                              hipStream_t stream) {
    const int*   inputs = (const int*)d_in[0];
    const float* h0     = (const float*)d_in[3];
    const float* c0     = (const float*)d_in[4];
    const float* emb    = (const float*)d_in[5];
    const float* W_ih   = (const float*)d_in[6];
    const float* W_hh   = (const float*)d_in[7];
    const float* b_ih   = (const float*)d_in[8];
    const float* b_hh   = (const float*)d_in[9];
    const float* W_out  = (const float*)d_in[10];
    const float* b_out  = (const float*)d_in[11];
    float* out = (float*)d_out;

    char* p = (char*)d_ws;
    auto alloc = [&](size_t bytes) { char* r = p; p += (bytes + 255) & ~255ull; return r; };
    float* lossbuf  = (float*)alloc((size_t)B_ * S_ * 4);
    int*   flags    = (int*)alloc(64 * 32 * 4);
    float* sp       = (float*)alloc((size_t)B_ * S_ * NGB * 5 * 4);          // 41 MB
    unsigned short* A1  = (unsigned short*)alloc((size_t)(S_ + 1) * 16384 * 2);
    unsigned short* A2  = (unsigned short*)alloc((size_t)(S_ + 1) * 16384 * 2);
    unsigned short* A3  = (unsigned short*)alloc((size_t)(S_ + 1) * 16384 * 2);
    unsigned short* Wph = (unsigned short*)alloc((size_t)NVT * 16 * 64 * 8 * 2);  // 32.8 MB
    unsigned short* Wpl = (unsigned short*)alloc((size_t)NVT * 16 * 64 * 8 * 2);
    unsigned short* B1f = (unsigned short*)alloc((size_t)RBLK * 16384 * 2);   // 2.1 MB
    unsigned short* B2f = (unsigned short*)alloc((size_t)RBLK * 16384 * 2);
    unsigned short* B3f = (unsigned short*)alloc((size_t)RBLK * 16384 * 2);
    float* XW       = (float*)alloc((size_t)S_ * B_ * G4_ * 4);               // 33.5 MB

    hipMemsetAsync(flags, 0, 64 * 32 * 4, stream);
    k_wsplit<<<(NVT * 16 * 64) / 256, 256, 0, stream>>>(W_out, Wph, Wpl);
    k_whh3<<<(RBLK * 2 * 16 * 64) / 256, 256, 0, stream>>>(W_hh, B1f, B2f, B3f);
    k_xw<<<dim3(8, S_), 256, 0, stream>>>(inputs, emb, W_ih, b_ih, b_hh, XW);
    k_recur<<<RBLK, 256, 0, stream>>>(h0, c0, B1f, B2f, B3f, XW, A1, A2, A3, flags);
    k_gemm<<<NGB, 256, 0, stream>>>(inputs, A1, A2, Wph, Wpl, b_out, sp);
    k_merge<<<(B_ * S_) / 16, 256, 0, stream>>>(sp, out, lossbuf);
    k_sum<<<1, 256, 0, stream>>>(lossbuf, out);
}

// Round 8
// 2856.598 us; speedup vs baseline: 6.4089x; 1.0227x over previous
//
#include <hip/hip_runtime.h>
#include <math.h>

#define B_ 32
#define S_ 128
#define H_ 512
#define V_ 32000
#define G4_ 2048
#define NVT 2000        // W_out 16-col v-tiles
#define NGB 500         // gemm blocks (64 cols each)
#define RBLK 64         // recurrence blocks (n-chunks of 8)

typedef __attribute__((ext_vector_type(8))) short bf8;   // 8 x bf16 fragment
typedef __attribute__((ext_vector_type(4))) float f4;    // MFMA accumulator

__device__ __forceinline__ unsigned short f2bf(float x) {
    union { float f; unsigned u; } v; v.f = x;
    unsigned r = v.u + 0x7FFFu + ((v.u >> 16) & 1u);     // RNE
    return (unsigned short)(r >> 16);
}
__device__ __forceinline__ float bf2f(unsigned short b) {
    union { unsigned u; float f; } v; v.u = ((unsigned)b) << 16; return v.f;
}
__device__ __forceinline__ float4 ldf4(const float* p) {
    return *reinterpret_cast<const float4*>(p);
}

// ------ split W_out into bf16 hi/lo, pre-swizzled to MFMA B-fragment order (once) ----
__global__ __launch_bounds__(256) void k_wsplit(const float* __restrict__ W,
                                                unsigned short* __restrict__ Wph,
                                                unsigned short* __restrict__ Wpl) {
    const size_t id = (size_t)blockIdx.x * 256 + threadIdx.x;   // 0 .. NVT*16*64-1
    const int lane = (int)(id & 63);
    const size_t fc = id >> 6;            // vt*16 + kc
    const int kc = (int)(fc & 15);
    const size_t vt = fc >> 4;
    const size_t r = vt * 16 + (lane & 15);
    const int k0 = kc * 32 + (lane >> 4) * 8;
    const float* src = W + r * H_ + k0;
    bf8 hv, lv;
#pragma unroll
    for (int e = 0; e < 8; ++e) {
        float x = src[e];
        unsigned short hb = f2bf(x);
        hv[e] = (short)hb;
        lv[e] = (short)f2bf(x - bf2f(hb));
    }
    *reinterpret_cast<bf8*>(Wph + id * 8) = hv;
    *reinterpret_cast<bf8*>(Wpl + id * 8) = lv;
}

// ------ split W_hh into THREE bf16 levels, B-fragment order grouped per recur block ---
__global__ __launch_bounds__(256) void k_whh3(const float* __restrict__ W,
                                              unsigned short* __restrict__ B1,
                                              unsigned short* __restrict__ B2,
                                              unsigned short* __restrict__ B3) {
    const size_t id = (size_t)blockIdx.x * 256 + threadIdx.x;  // ((g*2+nt)*16+kc)*64+lane
    const int lane = (int)(id & 63);
    const size_t fc = id >> 6;
    const int kc = (int)(fc & 15);
    const size_t gt = fc >> 4;
    const int nt = (int)(gt & 1);
    const int g = (int)(gt >> 1);
    const int c = lane & 15;
    const int q = nt * 2 + (c >> 3), nl = c & 7;
    const int row = q * 512 + g * 8 + nl;
    const int k0 = kc * 32 + (lane >> 4) * 8;
    const float* src = W + (size_t)row * H_ + k0;
    bf8 v1, v2, v3;
#pragma unroll
    for (int e = 0; e < 8; ++e) {
        float x = src[e];
        unsigned short a1 = f2bf(x);
        float r1 = x - bf2f(a1);
        unsigned short a2 = f2bf(r1);
        float r2 = r1 - bf2f(a2);
        v1[e] = (short)a1; v2[e] = (short)a2; v3[e] = (short)f2bf(r2);
    }
    *reinterpret_cast<bf8*>(B1 + id * 8) = v1;
    *reinterpret_cast<bf8*>(B2 + id * 8) = v2;
    *reinterpret_cast<bf8*>(B3 + id * 8) = v3;
}

// ------- precompute XW[t][b][j] = emb[tok[b,t]] @ W_ih^T + b_ih + b_hh (once) -------
__global__ __launch_bounds__(256) void k_xw(const int* __restrict__ inputs,
                                            const float* __restrict__ emb,
                                            const float* __restrict__ W_ih,
                                            const float* __restrict__ b_ih,
                                            const float* __restrict__ b_hh,
                                            float* __restrict__ XW) {
    __shared__ float es[16 * H_];
    const int tid = threadIdx.x;
    const int j = blockIdx.x * 256 + tid;
    const int t = blockIdx.y;
    const float bias = b_ih[j] + b_hh[j];
#pragma unroll
    for (int half = 0; half < 2; ++half) {
        __syncthreads();
        for (int idx = tid; idx < 16 * 128; idx += 256) {
            int b = idx >> 7, k4 = (idx & 127) << 2;
            int tok = inputs[(half * 16 + b) * S_ + t];
            *reinterpret_cast<float4*>(&es[b * H_ + k4]) = ldf4(emb + (size_t)tok * H_ + k4);
        }
        __syncthreads();
        float acc[16];
#pragma unroll
        for (int b = 0; b < 16; ++b) acc[b] = 0.f;
        for (int k = 0; k < H_; k += 4) {
            float4 wv = ldf4(W_ih + (size_t)j * H_ + k);
#pragma unroll
            for (int b = 0; b < 16; ++b) {
                float4 xv = *reinterpret_cast<const float4*>(&es[b * H_ + k]);
                acc[b] += wv.x * xv.x + wv.y * xv.y + wv.z * xv.z + wv.w * xv.w;
            }
        }
#pragma unroll
        for (int b = 0; b < 16; ++b)
            XW[(size_t)(t * B_ + half * 16 + b) * G4_ + j] = acc[b] + bias;
    }
}

// ---------------- the MFMA recurrence: 64 blocks, fence-free flag sync ----------------
__global__ __launch_bounds__(256)
void k_recur(const float* __restrict__ h0, const float* __restrict__ c0,
             const unsigned short* __restrict__ B1f, const unsigned short* __restrict__ B2f,
             const unsigned short* __restrict__ B3f, const float* __restrict__ XW,
             unsigned short* __restrict__ A1, unsigned short* __restrict__ A2,
             unsigned short* __restrict__ A3, int* __restrict__ flags) {
    __shared__ unsigned short wl1[16384], wl2[16384], wl3[16384];   // 3 x 32 KB
    __shared__ float glds[32][33];                                  // gates exchange
    const int g = blockIdx.x, tid = threadIdx.x;

    // load this block's W_hh fragments into LDS (once)
    {
        const size_t base = (size_t)g * 16384;
        for (int i = tid; i < 2048; i += 256) {
            reinterpret_cast<uint4*>(wl1)[i] = reinterpret_cast<const uint4*>(B1f + base)[i];
            reinterpret_cast<uint4*>(wl2)[i] = reinterpret_cast<const uint4*>(B2f + base)[i];
            reinterpret_cast<uint4*>(wl3)[i] = reinterpret_cast<const uint4*>(B3f + base)[i];
        }
    }
    // cell-thread identity: (b, nl); n = g*8+nl owned forever (c stays in a register)
    const int b = tid >> 3, nl = tid & 7;
    const int n = g * 8 + nl;
    const int kc_w = g >> 2, kg_w = g & 3, half_w = b >> 4, lane_w = kg_w * 16 + (b & 15);
    float c_reg = c0[b * H_ + n];
    float hn = h0[b * H_ + n];

    // publish h fragments: packed u32 relaxed agent-scope atomic stores (write-through
    // to L3, no fences, no dirty L2 lines left behind)
    auto write_frags = [&](int slot, float h) {
        unsigned short a1 = f2bf(h);
        float r1 = h - bf2f(a1);
        unsigned short a2 = f2bf(r1);
        unsigned short a3 = f2bf(r1 - bf2f(a2));
        unsigned v1 = a1, v2 = a2, v3 = a3;
        unsigned q1 = (unsigned)__shfl_xor((int)v1, 1);
        unsigned q2 = (unsigned)__shfl_xor((int)v2, 1);
        unsigned q3 = (unsigned)__shfl_xor((int)v3, 1);
        if ((nl & 1) == 0) {
            const size_t ix = ((((size_t)slot * 16 + kc_w) * 2 + half_w) * 64 + lane_w) * 8 + nl;
            __hip_atomic_store((unsigned*)(A1 + ix), v1 | (q1 << 16),
                               __ATOMIC_RELAXED, __HIP_MEMORY_SCOPE_AGENT);
            __hip_atomic_store((unsigned*)(A2 + ix), v2 | (q2 << 16),
                               __ATOMIC_RELAXED, __HIP_MEMORY_SCOPE_AGENT);
            __hip_atomic_store((unsigned*)(A3 + ix), v3 | (q3 << 16),
                               __ATOMIC_RELAXED, __HIP_MEMORY_SCOPE_AGENT);
        }
    };
    write_frags(0, hn);          // slot 0 = h_{-1} = h0
    asm volatile("s_waitcnt vmcnt(0)" ::: "memory");   // stores acked at L3
    __syncthreads();
    if (tid == 0)
        __hip_atomic_store(&flags[g * 32], 1, __ATOMIC_RELAXED, __HIP_MEMORY_SCOPE_AGENT);

    // wave roles for the MFMA phase
    const int wv = tid >> 6, lane = tid & 63;
    const int mt = wv >> 1, nt = wv & 1;
    const int cidx = lane & 15;

    for (int t = 0; t < S_; ++t) {
        // ---- wait for all blocks' h_{t-1} fragments (flag implies data at L3) ----
        if (tid < 64) {
            while (__hip_atomic_load(&flags[tid * 32], __ATOMIC_RELAXED,
                                     __HIP_MEMORY_SCOPE_AGENT) < t + 1)
                __builtin_amdgcn_s_sleep(1);
        }
        __syncthreads();
        // ---- 6-term MFMA gates: [32 x 512] x [512 x 32jl] (plain loads: slot t is
        //      a fresh address range, reader caches cannot hold stale copies) ----
        f4 acc = {0.f, 0.f, 0.f, 0.f};
        const unsigned short* a1p = A1 + ((((size_t)t * 16) * 2 + mt) * 64 + lane) * 8;
        const unsigned short* a2p = A2 + ((((size_t)t * 16) * 2 + mt) * 64 + lane) * 8;
        const unsigned short* a3p = A3 + ((((size_t)t * 16) * 2 + mt) * 64 + lane) * 8;
        const unsigned short* b1p = wl1 + ((size_t)(nt * 16) * 64 + lane) * 8;
        const unsigned short* b2p = wl2 + ((size_t)(nt * 16) * 64 + lane) * 8;
        const unsigned short* b3p = wl3 + ((size_t)(nt * 16) * 64 + lane) * 8;
#pragma unroll 4
        for (int kc = 0; kc < 16; ++kc) {
            bf8 A1v = *reinterpret_cast<const bf8*>(a1p + (size_t)kc * 1024);
            bf8 A2v = *reinterpret_cast<const bf8*>(a2p + (size_t)kc * 1024);
            bf8 A3v = *reinterpret_cast<const bf8*>(a3p + (size_t)kc * 1024);
            bf8 B1v = *reinterpret_cast<const bf8*>(b1p + (size_t)kc * 512);
            bf8 B2v = *reinterpret_cast<const bf8*>(b2p + (size_t)kc * 512);
            bf8 B3v = *reinterpret_cast<const bf8*>(b3p + (size_t)kc * 512);
            acc = __builtin_amdgcn_mfma_f32_16x16x32_bf16(A1v, B1v, acc, 0, 0, 0);
            acc = __builtin_amdgcn_mfma_f32_16x16x32_bf16(A1v, B2v, acc, 0, 0, 0);
            acc = __builtin_amdgcn_mfma_f32_16x16x32_bf16(A2v, B1v, acc, 0, 0, 0);
            acc = __builtin_amdgcn_mfma_f32_16x16x32_bf16(A2v, B2v, acc, 0, 0, 0);
            acc = __builtin_amdgcn_mfma_f32_16x16x32_bf16(A1v, B3v, acc, 0, 0, 0);
            acc = __builtin_amdgcn_mfma_f32_16x16x32_bf16(A3v, B1v, acc, 0, 0, 0);
        }
        // ---- stage gates to LDS: C layout col=lane&15 (jl), row=(lane>>4)*4+r (b) ----
#pragma unroll
        for (int r = 0; r < 4; ++r)
            glds[mt * 16 + (lane >> 4) * 4 + r][nt * 16 + cidx] = acc[r];
        __syncthreads();
        // ---- cell: activations + state update (c in register) ----
        const float* xwp = XW + ((size_t)t * B_ + b) * G4_;
        const float s_i = glds[b][nl]      + xwp[0 * 512 + n];
        const float s_f = glds[b][8 + nl]  + xwp[1 * 512 + n];
        const float s_g = glds[b][16 + nl] + xwp[2 * 512 + n];
        const float s_o = glds[b][24 + nl] + xwp[3 * 512 + n];
        const float ig = 1.f / (1.f + expf(-s_i));
        const float fg = 1.f / (1.f + expf(-s_f));
        const float gg = tanhf(s_g);
        const float og = 1.f / (1.f + expf(-s_o));
        c_reg = fg * c_reg + ig * gg;
        hn = og * tanhf(c_reg);
        write_frags(t + 1, hn);
        asm volatile("s_waitcnt vmcnt(0)" ::: "memory");   // h_t fragments at L3
        __syncthreads();
        if (tid == 0)
            __hip_atomic_store(&flags[g * 32], t + 2, __ATOMIC_RELAXED,
                               __HIP_MEMORY_SCOPE_AGENT);
    }
}

// ------- batched logits GEMM: W fragments resident in REGISTERS, A streamed ---------
__global__ __launch_bounds__(256) void k_gemm(const int* __restrict__ inputs,
                                              const unsigned short* __restrict__ Ah,
                                              const unsigned short* __restrict__ Al,
                                              const unsigned short* __restrict__ Wph,
                                              const unsigned short* __restrict__ Wpl,
                                              const float* __restrict__ b_out,
                                              float* __restrict__ sp) {
    __shared__ float slds[B_][68];
    const int tid = threadIdx.x;
    const int w = tid >> 6, lane = tid & 63;
    const int vt = blockIdx.x * 4 + w;
    const int v0 = blockIdx.x * 64;
    const int c = lane & 15, kg = lane >> 4;
    const int bb = tid >> 3, sub = tid & 7;

    // ---- one-time: this wave's 16-col W slice into registers (32 x bf8 = 128 VGPR) ----
    bf8 Bh[16], Bl[16];
#pragma unroll
    for (int kc = 0; kc < 16; ++kc) {
        const size_t wb = (((size_t)vt * 16 + kc) * 64 + lane) * 8;
        Bh[kc] = *reinterpret_cast<const bf8*>(Wph + wb);
        Bl[kc] = *reinterpret_cast<const bf8*>(Wpl + wb);
    }

    for (int mt = 0; mt < S_; ++mt) {
        f4 acc0 = {0.f, 0.f, 0.f, 0.f}, acc1 = {0.f, 0.f, 0.f, 0.f};
        const unsigned short* a1p = Ah + ((((size_t)(mt + 1) * 16) * 2) * 64 + lane) * 8;
        const unsigned short* a2p = Al + ((((size_t)(mt + 1) * 16) * 2) * 64 + lane) * 8;
#pragma unroll 4
        for (int kc = 0; kc < 16; ++kc) {
            bf8 A0h = *reinterpret_cast<const bf8*>(a1p + (size_t)kc * 1024);
            bf8 A1h = *reinterpret_cast<const bf8*>(a1p + (size_t)kc * 1024 + 512);
            bf8 A0l = *reinterpret_cast<const bf8*>(a2p + (size_t)kc * 1024);
            bf8 A1l = *reinterpret_cast<const bf8*>(a2p + (size_t)kc * 1024 + 512);
            acc0 = __builtin_amdgcn_mfma_f32_16x16x32_bf16(A0h, Bh[kc], acc0, 0, 0, 0);
            acc1 = __builtin_amdgcn_mfma_f32_16x16x32_bf16(A1h, Bh[kc], acc1, 0, 0, 0);
            acc0 = __builtin_amdgcn_mfma_f32_16x16x32_bf16(A0l, Bh[kc], acc0, 0, 0, 0);
            acc1 = __builtin_amdgcn_mfma_f32_16x16x32_bf16(A1l, Bh[kc], acc1, 0, 0, 0);
            acc0 = __builtin_amdgcn_mfma_f32_16x16x32_bf16(A0h, Bl[kc], acc0, 0, 0, 0);
            acc1 = __builtin_amdgcn_mfma_f32_16x16x32_bf16(A1h, Bl[kc], acc1, 0, 0, 0);
        }
        __syncthreads();                                // prev epilogue's slds reads done
#pragma unroll
        for (int r = 0; r < 4; ++r) {
            slds[kg * 4 + r][w * 16 + c] = acc0[r];
            slds[16 + kg * 4 + r][w * 16 + c] = acc1[r];
        }
        __syncthreads();
        const int tok = inputs[bb * S_ + mt];
        float m = -INFINITY, s = 0.f, mv = -INFINITY, tv = -INFINITY;
        int mi = 0x7fffffff;
#pragma unroll
        for (int q = 0; q < 8; ++q) {
            const int vl = sub * 8 + q, v = v0 + vl;
            float x = slds[bb][vl] + b_out[v];
            float nm = fmaxf(m, x);
            s = s * __expf(m - nm) + __expf(x - nm);
            m = nm;
            if (x > mv) { mv = x; mi = v; }
            if (v == tok) tv = x;
        }
#pragma unroll
        for (int off = 1; off < 8; off <<= 1) {
            float cm = __shfl_xor(m, off), cs = __shfl_xor(s, off);
            float cmv = __shfl_xor(mv, off), ctv = __shfl_xor(tv, off);
            int cmi = __shfl_xor(mi, off);
            float nm = fmaxf(m, cm);
            s = s * __expf(m - nm) + cs * __expf(cm - nm);
            m = nm;
            if (cmv > mv || (cmv == mv && cmi < mi)) { mv = cmv; mi = cmi; }
            tv = fmaxf(tv, ctv);
        }
        if (sub == 0) {
            float* o = sp + ((size_t)(mt * 32 + bb) * NGB + blockIdx.x) * 5;
            o[0] = m; o[1] = s; o[2] = mv; o[3] = (float)mi; o[4] = tv;
        }
    }
}

// ---------------- merge 500 tile-partials per row -> symbols + per-row logp ---------
__global__ __launch_bounds__(256) void k_merge(const float* __restrict__ sp,
                                               float* __restrict__ out,
                                               float* __restrict__ lossbuf) {
    const int tid = threadIdx.x;
    const int mi16 = tid >> 4, l16 = tid & 15;
    const int m = blockIdx.x * 16 + mi16;
    float mm = -INFINITY, s = 0.f, mv = -INFINITY, tv = -INFINITY;
    int ai = 0x7fffffff;
    for (int i = l16; i < NGB; i += 16) {
        const float* o = sp + ((size_t)m * NGB + i) * 5;
        float cm = o[0], cs = o[1], cmv = o[2], ctv = o[4];
        int cmi = (int)o[3];
        float nm = fmaxf(mm, cm);
        s = s * expf(mm - nm) + cs * expf(cm - nm);
        mm = nm;
        if (cmv > mv || (cmv == mv && cmi < ai)) { mv = cmv; ai = cmi; }
        tv = fmaxf(tv, ctv);
    }
#pragma unroll
    for (int off = 1; off < 16; off <<= 1) {
        float cm = __shfl_xor(mm, off), cs = __shfl_xor(s, off);
        float cmv = __shfl_xor(mv, off), ctv = __shfl_xor(tv, off);
        int cmi = __shfl_xor(ai, off);
        float nm = fmaxf(mm, cm);
        s = s * expf(mm - nm) + cs * expf(cm - nm);
        mm = nm;
        if (cmv > mv || (cmv == mv && cmi < ai)) { mv = cmv; ai = cmi; }
        tv = fmaxf(tv, ctv);
    }
    if (l16 == 0) {
        const float logZ = mm + logf(s);
        const int t = m >> 5, b = m & 31;
        out[1 + b * S_ + t] = (float)ai;
        lossbuf[m] = tv - logZ;
    }
}

// ---------------- final: deterministic sum of per-row losses ----------------
__global__ __launch_bounds__(256) void k_sum(const float* __restrict__ lossbuf,
                                             float* __restrict__ out) {
    const int tid = threadIdx.x;
    float a = 0.f;
    for (int i = tid; i < B_ * S_; i += 256) a += lossbuf[i];
    __shared__ float red[256];
    red[tid] = a;
    __syncthreads();
    for (int off = 128; off > 0; off >>= 1) {
        if (tid < off) red[tid] += red[tid + off];
        __syncthreads();
    }
    if (tid == 0) out[0] = -red[0] / (float)B_;
}

extern "C" void kernel_launch(void* const* d_in, const int* in_sizes, int n_in,
                              void* d_out, int out_size, void* d_ws, size_t ws_size,
                              hipStream_t stream) {
    const int*   inputs = (const int*)d_in[0];
    const float* h0     = (const float*)d_in[3];
    const float* c0     = (const float*)d_in[4];
    const float* emb    = (const float*)d_in[5];
    const float* W_ih   = (const float*)d_in[6];
    const float* W_hh   = (const float*)d_in[7];
    const float* b_ih   = (const float*)d_in[8];
    const float* b_hh   = (const float*)d_in[9];
    const float* W_out  = (const float*)d_in[10];
    const float* b_out  = (const float*)d_in[11];
    float* out = (float*)d_out;

    char* p = (char*)d_ws;
    auto alloc = [&](size_t bytes) { char* r = p; p += (bytes + 255) & ~255ull; return r; };
    float* lossbuf  = (float*)alloc((size_t)B_ * S_ * 4);
    int*   flags    = (int*)alloc(64 * 32 * 4);
    float* sp       = (float*)alloc((size_t)B_ * S_ * NGB * 5 * 4);          // 41 MB
    unsigned short* A1  = (unsigned short*)alloc((size_t)(S_ + 1) * 16384 * 2);
    unsigned short* A2  = (unsigned short*)alloc((size_t)(S_ + 1) * 16384 * 2);
    unsigned short* A3  = (unsigned short*)alloc((size_t)(S_ + 1) * 16384 * 2);
    unsigned short* Wph = (unsigned short*)alloc((size_t)NVT * 16 * 64 * 8 * 2);  // 32.8 MB
    unsigned short* Wpl = (unsigned short*)alloc((size_t)NVT * 16 * 64 * 8 * 2);
    unsigned short* B1f = (unsigned short*)alloc((size_t)RBLK * 16384 * 2);   // 2.1 MB
    unsigned short* B2f = (unsigned short*)alloc((size_t)RBLK * 16384 * 2);
    unsigned short* B3f = (unsigned short*)alloc((size_t)RBLK * 16384 * 2);
    float* XW       = (float*)alloc((size_t)S_ * B_ * G4_ * 4);               // 33.5 MB

    hipMemsetAsync(flags, 0, 64 * 32 * 4, stream);
    k_wsplit<<<(NVT * 16 * 64) / 256, 256, 0, stream>>>(W_out, Wph, Wpl);
    k_whh3<<<(RBLK * 2 * 16 * 64) / 256, 256, 0, stream>>>(W_hh, B1f, B2f, B3f);
    k_xw<<<dim3(8, S_), 256, 0, stream>>>(inputs, emb, W_ih, b_ih, b_hh, XW);
    k_recur<<<RBLK, 256, 0, stream>>>(h0, c0, B1f, B2f, B3f, XW, A1, A2, A3, flags);
    k_gemm<<<NGB, 256, 0, stream>>>(inputs, A1, A2, Wph, Wpl, b_out, sp);
    k_merge<<<(B_ * S_) / 16, 256, 0, stream>>>(sp, out, lossbuf);
    k_sum<<<1, 256, 0, stream>>>(lossbuf, out);
}

// Round 9
// 1852.647 us; speedup vs baseline: 9.8818x; 1.5419x over previous
//
#include <hip/hip_runtime.h>
#include <math.h>

#define B_ 32
#define S_ 128
#define H_ 512
#define V_ 32000
#define G4_ 2048
#define NVT 2000        // W_out 16-col v-tiles
#define NGB 500         // gemm blocks (64 cols each)
#define RBLK 64         // recurrence blocks (n-chunks of 8)

typedef __attribute__((ext_vector_type(8))) short bf8;   // 8 x bf16 fragment
typedef __attribute__((ext_vector_type(4))) float f4;    // MFMA accumulator

__device__ __forceinline__ unsigned short f2bf(float x) {
    union { float f; unsigned u; } v; v.f = x;
    unsigned r = v.u + 0x7FFFu + ((v.u >> 16) & 1u);     // RNE
    return (unsigned short)(r >> 16);
}
__device__ __forceinline__ float bf2f(unsigned short b) {
    union { unsigned u; float f; } v; v.u = ((unsigned)b) << 16; return v.f;
}
__device__ __forceinline__ float4 ldf4(const float* p) {
    return *reinterpret_cast<const float4*>(p);
}

// ------ split W_out into bf16 hi/lo, pre-swizzled to MFMA B-fragment order (once) ----
__global__ __launch_bounds__(256) void k_wsplit(const float* __restrict__ W,
                                                unsigned short* __restrict__ Wph,
                                                unsigned short* __restrict__ Wpl) {
    const size_t id = (size_t)blockIdx.x * 256 + threadIdx.x;   // 0 .. NVT*16*64-1
    const int lane = (int)(id & 63);
    const size_t fc = id >> 6;            // vt*16 + kc
    const int kc = (int)(fc & 15);
    const size_t vt = fc >> 4;
    const size_t r = vt * 16 + (lane & 15);
    const int k0 = kc * 32 + (lane >> 4) * 8;
    const float* src = W + r * H_ + k0;
    bf8 hv, lv;
#pragma unroll
    for (int e = 0; e < 8; ++e) {
        float x = src[e];
        unsigned short hb = f2bf(x);
        hv[e] = (short)hb;
        lv[e] = (short)f2bf(x - bf2f(hb));
    }
    *reinterpret_cast<bf8*>(Wph + id * 8) = hv;
    *reinterpret_cast<bf8*>(Wpl + id * 8) = lv;
}

// ------ split W_hh into THREE bf16 levels, B-fragment order grouped per recur block ---
__global__ __launch_bounds__(256) void k_whh3(const float* __restrict__ W,
                                              unsigned short* __restrict__ B1,
                                              unsigned short* __restrict__ B2,
                                              unsigned short* __restrict__ B3) {
    const size_t id = (size_t)blockIdx.x * 256 + threadIdx.x;  // ((g*2+nt)*16+kc)*64+lane
    const int lane = (int)(id & 63);
    const size_t fc = id >> 6;
    const int kc = (int)(fc & 15);
    const size_t gt = fc >> 4;
    const int nt = (int)(gt & 1);
    const int g = (int)(gt >> 1);
    const int c = lane & 15;
    const int q = nt * 2 + (c >> 3), nl = c & 7;
    const int row = q * 512 + g * 8 + nl;
    const int k0 = kc * 32 + (lane >> 4) * 8;
    const float* src = W + (size_t)row * H_ + k0;
    bf8 v1, v2, v3;
#pragma unroll
    for (int e = 0; e < 8; ++e) {
        float x = src[e];
        unsigned short a1 = f2bf(x);
        float r1 = x - bf2f(a1);
        unsigned short a2 = f2bf(r1);
        float r2 = r1 - bf2f(a2);
        v1[e] = (short)a1; v2[e] = (short)a2; v3[e] = (short)f2bf(r2);
    }
    *reinterpret_cast<bf8*>(B1 + id * 8) = v1;
    *reinterpret_cast<bf8*>(B2 + id * 8) = v2;
    *reinterpret_cast<bf8*>(B3 + id * 8) = v3;
}

// ------- precompute XW[t][b][j] = emb[tok[b,t]] @ W_ih^T + b_ih + b_hh (once) -------
__global__ __launch_bounds__(256) void k_xw(const int* __restrict__ inputs,
                                            const float* __restrict__ emb,
                                            const float* __restrict__ W_ih,
                                            const float* __restrict__ b_ih,
                                            const float* __restrict__ b_hh,
                                            float* __restrict__ XW) {
    __shared__ float es[16 * H_];
    const int tid = threadIdx.x;
    const int j = blockIdx.x * 256 + tid;
    const int t = blockIdx.y;
    const float bias = b_ih[j] + b_hh[j];
#pragma unroll
    for (int half = 0; half < 2; ++half) {
        __syncthreads();
        for (int idx = tid; idx < 16 * 128; idx += 256) {
            int b = idx >> 7, k4 = (idx & 127) << 2;
            int tok = inputs[(half * 16 + b) * S_ + t];
            *reinterpret_cast<float4*>(&es[b * H_ + k4]) = ldf4(emb + (size_t)tok * H_ + k4);
        }
        __syncthreads();
        float acc[16];
#pragma unroll
        for (int b = 0; b < 16; ++b) acc[b] = 0.f;
        for (int k = 0; k < H_; k += 4) {
            float4 wv = ldf4(W_ih + (size_t)j * H_ + k);
#pragma unroll
            for (int b = 0; b < 16; ++b) {
                float4 xv = *reinterpret_cast<const float4*>(&es[b * H_ + k]);
                acc[b] += wv.x * xv.x + wv.y * xv.y + wv.z * xv.z + wv.w * xv.w;
            }
        }
#pragma unroll
        for (int b = 0; b < 16; ++b)
            XW[(size_t)(t * B_ + half * 16 + b) * G4_ + j] = acc[b] + bias;
    }
}

// ---------------- the MFMA recurrence: 64 blocks, fence-free flag sync ----------------
__global__ __launch_bounds__(256)
void k_recur(const float* __restrict__ h0, const float* __restrict__ c0,
             const unsigned short* __restrict__ B1f, const unsigned short* __restrict__ B2f,
             const unsigned short* __restrict__ B3f, const float* __restrict__ XW,
             unsigned short* __restrict__ A1, unsigned short* __restrict__ A2,
             unsigned short* __restrict__ A3, int* __restrict__ flags) {
    __shared__ unsigned short wl1[16384], wl2[16384], wl3[16384];   // 3 x 32 KB
    __shared__ float glds[32][33];                                  // gates exchange
    const int g = blockIdx.x, tid = threadIdx.x;

    // load this block's W_hh fragments into LDS (once)
    {
        const size_t base = (size_t)g * 16384;
        for (int i = tid; i < 2048; i += 256) {
            reinterpret_cast<uint4*>(wl1)[i] = reinterpret_cast<const uint4*>(B1f + base)[i];
            reinterpret_cast<uint4*>(wl2)[i] = reinterpret_cast<const uint4*>(B2f + base)[i];
            reinterpret_cast<uint4*>(wl3)[i] = reinterpret_cast<const uint4*>(B3f + base)[i];
        }
    }
    // cell-thread identity: (b, nl); n = g*8+nl owned forever (c stays in a register)
    const int b = tid >> 3, nl = tid & 7;
    const int n = g * 8 + nl;
    const int kc_w = g >> 2, kg_w = g & 3, half_w = b >> 4, lane_w = kg_w * 16 + (b & 15);
    float c_reg = c0[b * H_ + n];
    float hn = h0[b * H_ + n];

    // publish h fragments: packed u32 relaxed agent-scope atomic stores (write-through
    // to L3, no fences, no dirty L2 lines left behind)
    auto write_frags = [&](int slot, float h) {
        unsigned short a1 = f2bf(h);
        float r1 = h - bf2f(a1);
        unsigned short a2 = f2bf(r1);
        unsigned short a3 = f2bf(r1 - bf2f(a2));
        unsigned v1 = a1, v2 = a2, v3 = a3;
        unsigned q1 = (unsigned)__shfl_xor((int)v1, 1);
        unsigned q2 = (unsigned)__shfl_xor((int)v2, 1);
        unsigned q3 = (unsigned)__shfl_xor((int)v3, 1);
        if ((nl & 1) == 0) {
            const size_t ix = ((((size_t)slot * 16 + kc_w) * 2 + half_w) * 64 + lane_w) * 8 + nl;
            __hip_atomic_store((unsigned*)(A1 + ix), v1 | (q1 << 16),
                               __ATOMIC_RELAXED, __HIP_MEMORY_SCOPE_AGENT);
            __hip_atomic_store((unsigned*)(A2 + ix), v2 | (q2 << 16),
                               __ATOMIC_RELAXED, __HIP_MEMORY_SCOPE_AGENT);
            __hip_atomic_store((unsigned*)(A3 + ix), v3 | (q3 << 16),
                               __ATOMIC_RELAXED, __HIP_MEMORY_SCOPE_AGENT);
        }
    };
    write_frags(0, hn);          // slot 0 = h_{-1} = h0
    asm volatile("s_waitcnt vmcnt(0)" ::: "memory");   // stores acked at L3
    __syncthreads();
    if (tid == 0)
        __hip_atomic_store(&flags[g * 32], 1, __ATOMIC_RELAXED, __HIP_MEMORY_SCOPE_AGENT);

    // wave roles for the MFMA phase
    const int wv = tid >> 6, lane = tid & 63;
    const int mt = wv >> 1, nt = wv & 1;
    const int cidx = lane & 15;

    for (int t = 0; t < S_; ++t) {
        // ---- wait for all blocks' h_{t-1} fragments (flag implies data at L3) ----
        if (tid < 64) {
            while (__hip_atomic_load(&flags[tid * 32], __ATOMIC_RELAXED,
                                     __HIP_MEMORY_SCOPE_AGENT) < t + 1)
                __builtin_amdgcn_s_sleep(1);
        }
        __syncthreads();
        // ---- 6-term MFMA gates: [32 x 512] x [512 x 32jl] (plain loads: slot t is
        //      a fresh address range, reader caches cannot hold stale copies) ----
        f4 acc = {0.f, 0.f, 0.f, 0.f};
        const unsigned short* a1p = A1 + ((((size_t)t * 16) * 2 + mt) * 64 + lane) * 8;
        const unsigned short* a2p = A2 + ((((size_t)t * 16) * 2 + mt) * 64 + lane) * 8;
        const unsigned short* a3p = A3 + ((((size_t)t * 16) * 2 + mt) * 64 + lane) * 8;
        const unsigned short* b1p = wl1 + ((size_t)(nt * 16) * 64 + lane) * 8;
        const unsigned short* b2p = wl2 + ((size_t)(nt * 16) * 64 + lane) * 8;
        const unsigned short* b3p = wl3 + ((size_t)(nt * 16) * 64 + lane) * 8;
#pragma unroll 4
        for (int kc = 0; kc < 16; ++kc) {
            bf8 A1v = *reinterpret_cast<const bf8*>(a1p + (size_t)kc * 1024);
            bf8 A2v = *reinterpret_cast<const bf8*>(a2p + (size_t)kc * 1024);
            bf8 A3v = *reinterpret_cast<const bf8*>(a3p + (size_t)kc * 1024);
            bf8 B1v = *reinterpret_cast<const bf8*>(b1p + (size_t)kc * 512);
            bf8 B2v = *reinterpret_cast<const bf8*>(b2p + (size_t)kc * 512);
            bf8 B3v = *reinterpret_cast<const bf8*>(b3p + (size_t)kc * 512);
            acc = __builtin_amdgcn_mfma_f32_16x16x32_bf16(A1v, B1v, acc, 0, 0, 0);
            acc = __builtin_amdgcn_mfma_f32_16x16x32_bf16(A1v, B2v, acc, 0, 0, 0);
            acc = __builtin_amdgcn_mfma_f32_16x16x32_bf16(A2v, B1v, acc, 0, 0, 0);
            acc = __builtin_amdgcn_mfma_f32_16x16x32_bf16(A2v, B2v, acc, 0, 0, 0);
            acc = __builtin_amdgcn_mfma_f32_16x16x32_bf16(A1v, B3v, acc, 0, 0, 0);
            acc = __builtin_amdgcn_mfma_f32_16x16x32_bf16(A3v, B1v, acc, 0, 0, 0);
        }
        // ---- stage gates to LDS: C layout col=lane&15 (jl), row=(lane>>4)*4+r (b) ----
#pragma unroll
        for (int r = 0; r < 4; ++r)
            glds[mt * 16 + (lane >> 4) * 4 + r][nt * 16 + cidx] = acc[r];
        __syncthreads();
        // ---- cell: activations + state update (c in register) ----
        const float* xwp = XW + ((size_t)t * B_ + b) * G4_;
        const float s_i = glds[b][nl]      + xwp[0 * 512 + n];
        const float s_f = glds[b][8 + nl]  + xwp[1 * 512 + n];
        const float s_g = glds[b][16 + nl] + xwp[2 * 512 + n];
        const float s_o = glds[b][24 + nl] + xwp[3 * 512 + n];
        const float ig = 1.f / (1.f + expf(-s_i));
        const float fg = 1.f / (1.f + expf(-s_f));
        const float gg = tanhf(s_g);
        const float og = 1.f / (1.f + expf(-s_o));
        c_reg = fg * c_reg + ig * gg;
        hn = og * tanhf(c_reg);
        write_frags(t + 1, hn);
        asm volatile("s_waitcnt vmcnt(0)" ::: "memory");   // h_t fragments at L3
        __syncthreads();
        if (tid == 0)
            __hip_atomic_store(&flags[g * 32], t + 2, __ATOMIC_RELAXED,
                               __HIP_MEMORY_SCOPE_AGENT);
    }
}

// ------- batched logits GEMM: W truly register-resident (pinned), A streamed --------
__global__ __launch_bounds__(256, 2) void k_gemm(const int* __restrict__ inputs,
                                                 const unsigned short* __restrict__ Ah,
                                                 const unsigned short* __restrict__ Al,
                                                 const unsigned short* __restrict__ Wph,
                                                 const unsigned short* __restrict__ Wpl,
                                                 const float* __restrict__ b_out,
                                                 float* __restrict__ sp) {
    __shared__ float slds[B_][68];
    const int tid = threadIdx.x;
    const int w = tid >> 6, lane = tid & 63;
    const int vt = blockIdx.x * 4 + w;
    const int v0 = blockIdx.x * 64;
    const int c = lane & 15, kg = lane >> 4;
    const int bb = tid >> 3, sub = tid & 7;

    // ---- one-time: W slice -> registers. FULL unroll (compile-time indices) + asm pin
    //      so the compiler cannot rematerialize the loads inside the mt loop. ----
    bf8 Bh[16], Bl[16];
#pragma unroll
    for (int kc = 0; kc < 16; ++kc) {
        const size_t wb = (((size_t)vt * 16 + kc) * 64 + lane) * 8;
        Bh[kc] = *reinterpret_cast<const bf8*>(Wph + wb);
        Bl[kc] = *reinterpret_cast<const bf8*>(Wpl + wb);
    }
#pragma unroll
    for (int kc = 0; kc < 16; ++kc)
        asm volatile("" : "+v"(Bh[kc]), "+v"(Bl[kc]));

    // mt-invariant epilogue operands
    float bo[8];
#pragma unroll
    for (int q = 0; q < 8; ++q) bo[q] = b_out[v0 + sub * 8 + q];

    for (int mt = 0; mt < S_; ++mt) {
        f4 acc0 = {0.f, 0.f, 0.f, 0.f}, acc1 = {0.f, 0.f, 0.f, 0.f};
        const unsigned short* a1p = Ah + ((((size_t)(mt + 1) * 16) * 2) * 64 + lane) * 8;
        const unsigned short* a2p = Al + ((((size_t)(mt + 1) * 16) * 2) * 64 + lane) * 8;
#pragma unroll
        for (int kc = 0; kc < 16; ++kc) {
            bf8 A0h = *reinterpret_cast<const bf8*>(a1p + (size_t)kc * 1024);
            bf8 A1h = *reinterpret_cast<const bf8*>(a1p + (size_t)kc * 1024 + 512);
            bf8 A0l = *reinterpret_cast<const bf8*>(a2p + (size_t)kc * 1024);
            bf8 A1l = *reinterpret_cast<const bf8*>(a2p + (size_t)kc * 1024 + 512);
            acc0 = __builtin_amdgcn_mfma_f32_16x16x32_bf16(A0h, Bh[kc], acc0, 0, 0, 0);
            acc1 = __builtin_amdgcn_mfma_f32_16x16x32_bf16(A1h, Bh[kc], acc1, 0, 0, 0);
            acc0 = __builtin_amdgcn_mfma_f32_16x16x32_bf16(A0l, Bh[kc], acc0, 0, 0, 0);
            acc1 = __builtin_amdgcn_mfma_f32_16x16x32_bf16(A1l, Bh[kc], acc1, 0, 0, 0);
            acc0 = __builtin_amdgcn_mfma_f32_16x16x32_bf16(A0h, Bl[kc], acc0, 0, 0, 0);
            acc1 = __builtin_amdgcn_mfma_f32_16x16x32_bf16(A1h, Bl[kc], acc1, 0, 0, 0);
        }
        __syncthreads();                                // prev epilogue's slds reads done
#pragma unroll
        for (int r = 0; r < 4; ++r) {
            slds[kg * 4 + r][w * 16 + c] = acc0[r];
            slds[16 + kg * 4 + r][w * 16 + c] = acc1[r];
        }
        __syncthreads();
        const int tok = inputs[bb * S_ + mt];
        float m = -INFINITY, s = 0.f, mv = -INFINITY, tv = -INFINITY;
        int mi = 0x7fffffff;
#pragma unroll
        for (int q = 0; q < 8; ++q) {
            const int vl = sub * 8 + q, v = v0 + vl;
            float x = slds[bb][vl] + bo[q];
            float nm = fmaxf(m, x);
            s = s * __expf(m - nm) + __expf(x - nm);
            m = nm;
            if (x > mv) { mv = x; mi = v; }
            if (v == tok) tv = x;
        }
#pragma unroll
        for (int off = 1; off < 8; off <<= 1) {
            float cm = __shfl_xor(m, off), cs = __shfl_xor(s, off);
            float cmv = __shfl_xor(mv, off), ctv = __shfl_xor(tv, off);
            int cmi = __shfl_xor(mi, off);
            float nm = fmaxf(m, cm);
            s = s * __expf(m - nm) + cs * __expf(cm - nm);
            m = nm;
            if (cmv > mv || (cmv == mv && cmi < mi)) { mv = cmv; mi = cmi; }
            tv = fmaxf(tv, ctv);
        }
        if (sub == 0) {
            float* o = sp + ((size_t)(mt * 32 + bb) * NGB + blockIdx.x) * 5;
            o[0] = m; o[1] = s; o[2] = mv; o[3] = (float)mi; o[4] = tv;
        }
    }
}

// ---------------- merge 500 tile-partials per row -> symbols + per-row logp ---------
__global__ __launch_bounds__(256) void k_merge(const float* __restrict__ sp,
                                               float* __restrict__ out,
                                               float* __restrict__ lossbuf) {
    const int tid = threadIdx.x;
    const int mi16 = tid >> 4, l16 = tid & 15;
    const int m = blockIdx.x * 16 + mi16;
    float mm = -INFINITY, s = 0.f, mv = -INFINITY, tv = -INFINITY;
    int ai = 0x7fffffff;
    for (int i = l16; i < NGB; i += 16) {
        const float* o = sp + ((size_t)m * NGB + i) * 5;
        float cm = o[0], cs = o[1], cmv = o[2], ctv = o[4];
        int cmi = (int)o[3];
        float nm = fmaxf(mm, cm);
        s = s * expf(mm - nm) + cs * expf(cm - nm);
        mm = nm;
        if (cmv > mv || (cmv == mv && cmi < ai)) { mv = cmv; ai = cmi; }
        tv = fmaxf(tv, ctv);
    }
#pragma unroll
    for (int off = 1; off < 16; off <<= 1) {
        float cm = __shfl_xor(mm, off), cs = __shfl_xor(s, off);
        float cmv = __shfl_xor(mv, off), ctv = __shfl_xor(tv, off);
        int cmi = __shfl_xor(ai, off);
        float nm = fmaxf(mm, cm);
        s = s * expf(mm - nm) + cs * expf(cm - nm);
        mm = nm;
        if (cmv > mv || (cmv == mv && cmi < ai)) { mv = cmv; ai = cmi; }
        tv = fmaxf(tv, ctv);
    }
    if (l16 == 0) {
        const float logZ = mm + logf(s);
        const int t = m >> 5, b = m & 31;
        out[1 + b * S_ + t] = (float)ai;
        lossbuf[m] = tv - logZ;
    }
}

// ---------------- final: deterministic sum of per-row losses ----------------
__global__ __launch_bounds__(256) void k_sum(const float* __restrict__ lossbuf,
                                             float* __restrict__ out) {
    const int tid = threadIdx.x;
    float a = 0.f;
    for (int i = tid; i < B_ * S_; i += 256) a += lossbuf[i];
    __shared__ float red[256];
    red[tid] = a;
    __syncthreads();
    for (int off = 128; off > 0; off >>= 1) {
        if (tid < off) red[tid] += red[tid + off];
        __syncthreads();
    }
    if (tid == 0) out[0] = -red[0] / (float)B_;
}

extern "C" void kernel_launch(void* const* d_in, const int* in_sizes, int n_in,
                              void* d_out, int out_size, void* d_ws, size_t ws_size,
                              hipStream_t stream) {
    const int*   inputs = (const int*)d_in[0];
    const float* h0     = (const float*)d_in[3];
    const float* c0     = (const float*)d_in[4];
    const float* emb    = (const float*)d_in[5];
    const float* W_ih   = (const float*)d_in[6];
    const float* W_hh   = (const float*)d_in[7];
    const float* b_ih   = (const float*)d_in[8];
    const float* b_hh   = (const float*)d_in[9];
    const float* W_out  = (const float*)d_in[10];
    const float* b_out  = (const float*)d_in[11];
    float* out = (float*)d_out;

    char* p = (char*)d_ws;
    auto alloc = [&](size_t bytes) { char* r = p; p += (bytes + 255) & ~255ull; return r; };
    float* lossbuf  = (float*)alloc((size_t)B_ * S_ * 4);
    int*   flags    = (int*)alloc(64 * 32 * 4);
    float* sp       = (float*)alloc((size_t)B_ * S_ * NGB * 5 * 4);          // 41 MB
    unsigned short* A1  = (unsigned short*)alloc((size_t)(S_ + 1) * 16384 * 2);
    unsigned short* A2  = (unsigned short*)alloc((size_t)(S_ + 1) * 16384 * 2);
    unsigned short* A3  = (unsigned short*)alloc((size_t)(S_ + 1) * 16384 * 2);
    unsigned short* Wph = (unsigned short*)alloc((size_t)NVT * 16 * 64 * 8 * 2);  // 32.8 MB
    unsigned short* Wpl = (unsigned short*)alloc((size_t)NVT * 16 * 64 * 8 * 2);
    unsigned short* B1f = (unsigned short*)alloc((size_t)RBLK * 16384 * 2);   // 2.1 MB
    unsigned short* B2f = (unsigned short*)alloc((size_t)RBLK * 16384 * 2);
    unsigned short* B3f = (unsigned short*)alloc((size_t)RBLK * 16384 * 2);
    float* XW       = (float*)alloc((size_t)S_ * B_ * G4_ * 4);               // 33.5 MB

    hipMemsetAsync(flags, 0, 64 * 32 * 4, stream);
    k_wsplit<<<(NVT * 16 * 64) / 256, 256, 0, stream>>>(W_out, Wph, Wpl);
    k_whh3<<<(RBLK * 2 * 16 * 64) / 256, 256, 0, stream>>>(W_hh, B1f, B2f, B3f);
    k_xw<<<dim3(8, S_), 256, 0, stream>>>(inputs, emb, W_ih, b_ih, b_hh, XW);
    k_recur<<<RBLK, 256, 0, stream>>>(h0, c0, B1f, B2f, B3f, XW, A1, A2, A3, flags);
    k_gemm<<<NGB, 256, 0, stream>>>(inputs, A1, A2, Wph, Wpl, b_out, sp);
    k_merge<<<(B_ * S_) / 16, 256, 0, stream>>>(sp, out, lossbuf);
    k_sum<<<1, 256, 0, stream>>>(lossbuf, out);
}